// Round 1
// baseline (2346.952 us; speedup 1.0000x reference)
//
#include <hip/hip_runtime.h>
#include <math.h>

#define NB 16
#define NC 128
#define NHW 4096     // 64*64
#define NHWP 1024    // 32*32
#define NCQ 16       // C/8
#define NCV 64       // C/2

// ---------------------------------------------------------------- pool 2x2
__global__ __launch_bounds__(256) void pool_kernel(const float* __restrict__ x,
                                                   float* __restrict__ xp) {
  int idx = blockIdx.x * 256 + threadIdx.x;        // [0, NB*NC*NHWP)
  int j  = idx & 31;
  int i  = (idx >> 5) & 31;
  int bc = idx >> 10;
  const float* xr = x + (size_t)bc * NHW + (size_t)(2 * i) * 64 + 2 * j;
  float m0 = fmaxf(xr[0],  xr[1]);
  float m1 = fmaxf(xr[64], xr[65]);
  xp[idx] = fmaxf(m0, m1);
}

// ---------------------------------------------------------------- q = wq @ x
__global__ __launch_bounds__(256) void projq_kernel(const float* __restrict__ x,
    const float* __restrict__ wq, const float* __restrict__ bq,
    float* __restrict__ q) {
  __shared__ float swT[NC][NCQ];   // swT[c][o] = wq[o][c]
  __shared__ float sb[NCQ];
  int tid = threadIdx.x;
  for (int i = tid; i < NC * NCQ; i += 256) {
    int o = i >> 7, c = i & 127;
    swT[c][o] = wq[i];
  }
  if (tid < NCQ) sb[tid] = bq[tid];
  __syncthreads();
  int b = blockIdx.x >> 4;
  int n = ((blockIdx.x & 15) << 8) | tid;
  const float* xb = x + (size_t)b * NC * NHW + n;
  float acc[NCQ];
#pragma unroll
  for (int o = 0; o < NCQ; o++) acc[o] = sb[o];
  for (int c = 0; c < NC; c++) {
    float xv = xb[(size_t)c * NHW];
    const float4* wr = (const float4*)&swT[c][0];
#pragma unroll
    for (int o4 = 0; o4 < NCQ / 4; o4++) {
      float4 w = wr[o4];
      acc[4*o4+0] = fmaf(xv, w.x, acc[4*o4+0]);
      acc[4*o4+1] = fmaf(xv, w.y, acc[4*o4+1]);
      acc[4*o4+2] = fmaf(xv, w.z, acc[4*o4+2]);
      acc[4*o4+3] = fmaf(xv, w.w, acc[4*o4+3]);
    }
  }
  float* qb = q + (size_t)b * NCQ * NHW + n;
#pragma unroll
  for (int o = 0; o < NCQ; o++) qb[(size_t)o * NHW] = acc[o];
}

// --------------------------------------------------- k,v = {wk,wv} @ xp (fused)
// outputs transposed: kT[b][m][16], vT[b][m][64]
__global__ __launch_bounds__(256) void projkv_kernel(const float* __restrict__ xp,
    const float* __restrict__ wk, const float* __restrict__ bk,
    const float* __restrict__ wv, const float* __restrict__ bv,
    float* __restrict__ kT, float* __restrict__ vT) {
  __shared__ float swkT[NC][NCQ];   // [c][o]
  __shared__ float swvT[NC][NCV];   // [c][o]
  __shared__ float sbk[NCQ];
  __shared__ float sbv[NCV];
  int tid = threadIdx.x;
  for (int i = tid; i < NC * NCQ; i += 256) {
    int o = i >> 7, c = i & 127;
    swkT[c][o] = wk[i];
  }
  for (int i = tid; i < NC * NCV; i += 256) {
    int o = i >> 7, c = i & 127;
    swvT[c][o] = wv[i];
  }
  if (tid < NCQ) sbk[tid] = bk[tid];
  if (tid < NCV) sbv[tid] = bv[tid];
  __syncthreads();
  int b = blockIdx.x >> 2;
  int m = ((blockIdx.x & 3) << 8) | tid;
  const float* xb = xp + (size_t)b * NC * NHWP + m;
  float ak[NCQ], av[NCV];
#pragma unroll
  for (int o = 0; o < NCQ; o++) ak[o] = sbk[o];
#pragma unroll
  for (int o = 0; o < NCV; o++) av[o] = sbv[o];
  for (int c = 0; c < NC; c++) {
    float xv = xb[(size_t)c * NHWP];
    const float4* wkr = (const float4*)&swkT[c][0];
#pragma unroll
    for (int o4 = 0; o4 < NCQ / 4; o4++) {
      float4 w = wkr[o4];
      ak[4*o4+0] = fmaf(xv, w.x, ak[4*o4+0]);
      ak[4*o4+1] = fmaf(xv, w.y, ak[4*o4+1]);
      ak[4*o4+2] = fmaf(xv, w.z, ak[4*o4+2]);
      ak[4*o4+3] = fmaf(xv, w.w, ak[4*o4+3]);
    }
    const float4* wvr = (const float4*)&swvT[c][0];
#pragma unroll
    for (int o4 = 0; o4 < NCV / 4; o4++) {
      float4 w = wvr[o4];
      av[4*o4+0] = fmaf(xv, w.x, av[4*o4+0]);
      av[4*o4+1] = fmaf(xv, w.y, av[4*o4+1]);
      av[4*o4+2] = fmaf(xv, w.z, av[4*o4+2]);
      av[4*o4+3] = fmaf(xv, w.w, av[4*o4+3]);
    }
  }
  float4* kr = (float4*)(kT + ((size_t)b * NHWP + m) * NCQ);
#pragma unroll
  for (int o4 = 0; o4 < NCQ / 4; o4++)
    kr[o4] = make_float4(ak[4*o4+0], ak[4*o4+1], ak[4*o4+2], ak[4*o4+3]);
  float4* vr = (float4*)(vT + ((size_t)b * NHWP + m) * NCV);
#pragma unroll
  for (int o4 = 0; o4 < NCV / 4; o4++)
    vr[o4] = make_float4(av[4*o4+0], av[4*o4+1], av[4*o4+2], av[4*o4+3]);
}

// ------------------------------------------- fused scores + softmax + PV
// one thread per (n, m-quarter); single pass, no max subtraction (|s| <~ 8)
__global__ __launch_bounds__(256) void attn_kernel(const float* __restrict__ q,
    const float* __restrict__ kT, const float* __restrict__ vT,
    float* __restrict__ feat) {
  int tid  = threadIdx.x;
  int part = tid & 3;          // m quarter
  int nl   = tid >> 2;         // 0..63
  int b = blockIdx.x >> 6;
  int n = ((blockIdx.x & 63) << 6) | nl;
  const float* qb = q + (size_t)b * NCQ * NHW + n;
  float qv[NCQ];
#pragma unroll
  for (int o = 0; o < NCQ; o++) qv[o] = qb[(size_t)o * NHW];
  const float* kb = kT + (size_t)b * NHWP * NCQ;
  const float* vb = vT + (size_t)b * NHWP * NCV;
  float facc[NCV];
#pragma unroll
  for (int c = 0; c < NCV; c++) facc[c] = 0.f;
  float esum = 0.f;
  int m0 = part << 8;
#pragma unroll 2
  for (int mi = 0; mi < 256; mi++) {
    int m = m0 | mi;
    const float4* kr = (const float4*)(kb + (size_t)m * NCQ);
    float s = 0.f;
#pragma unroll
    for (int o4 = 0; o4 < 4; o4++) {
      float4 kv = kr[o4];
      s = fmaf(qv[4*o4+0], kv.x, s);
      s = fmaf(qv[4*o4+1], kv.y, s);
      s = fmaf(qv[4*o4+2], kv.z, s);
      s = fmaf(qv[4*o4+3], kv.w, s);
    }
    float e = __expf(s);
    esum += e;
    const float4* vr = (const float4*)(vb + (size_t)m * NCV);
#pragma unroll
    for (int c4 = 0; c4 < NCV / 4; c4++) {
      float4 vv = vr[c4];
      facc[4*c4+0] = fmaf(e, vv.x, facc[4*c4+0]);
      facc[4*c4+1] = fmaf(e, vv.y, facc[4*c4+1]);
      facc[4*c4+2] = fmaf(e, vv.z, facc[4*c4+2]);
      facc[4*c4+3] = fmaf(e, vv.w, facc[4*c4+3]);
    }
  }
  // combine the 4 m-quarters (lanes 4k..4k+3 share the same n)
  esum += __shfl_xor(esum, 1);
  esum += __shfl_xor(esum, 2);
#pragma unroll
  for (int c = 0; c < NCV; c++) {
    facc[c] += __shfl_xor(facc[c], 1);
    facc[c] += __shfl_xor(facc[c], 2);
  }
  float inv = 1.0f / esum;
  float* fb = feat + (size_t)b * NCV * NHW + n;
#pragma unroll
  for (int c = 0; c < NCV; c++) {            // static index, predicated write
    if ((c >> 4) == part) fb[(size_t)c * NHW] = facc[c] * inv;
  }
}

// -------------------------------------- out = gamma*(wa@feat + ba) + x
__global__ __launch_bounds__(256) void outproj_kernel(const float* __restrict__ feat,
    const float* __restrict__ wa, const float* __restrict__ ba,
    const float* __restrict__ gamma, const float* __restrict__ x,
    float* __restrict__ out) {
  __shared__ float swaT[NCV][16];   // swaT[c][o] = wa[ocbase+o][c]
  __shared__ float sba[16];
  int tid  = threadIdx.x;
  int ocg  = blockIdx.x & 7;
  int tile = (blockIdx.x >> 3) & 3;
  int b    = blockIdx.x >> 5;
  int ocbase = ocg * 16;
  for (int i = tid; i < NCV * 16; i += 256) {
    int c = i >> 4, o = i & 15;
    swaT[c][o] = wa[(size_t)(ocbase + o) * NCV + c];
  }
  if (tid < 16) sba[tid] = ba[ocbase + tid];
  __syncthreads();
  float g = gamma[0];
  int n0 = tile * 1024 + tid;      // handles n0, n0+256, n0+512, n0+768
  const float* fb = feat + (size_t)b * NCV * NHW;
  float acc[4][16];
#pragma unroll
  for (int r = 0; r < 4; r++)
#pragma unroll
    for (int o = 0; o < 16; o++) acc[r][o] = sba[o];
  for (int c = 0; c < NCV; c++) {
    const float* fr = fb + (size_t)c * NHW + n0;
    float f0 = fr[0], f1 = fr[256], f2 = fr[512], f3 = fr[768];
    const float4* wr = (const float4*)&swaT[c][0];
#pragma unroll
    for (int o4 = 0; o4 < 4; o4++) {
      float4 w = wr[o4];
      acc[0][4*o4+0] = fmaf(f0, w.x, acc[0][4*o4+0]);
      acc[0][4*o4+1] = fmaf(f0, w.y, acc[0][4*o4+1]);
      acc[0][4*o4+2] = fmaf(f0, w.z, acc[0][4*o4+2]);
      acc[0][4*o4+3] = fmaf(f0, w.w, acc[0][4*o4+3]);
      acc[1][4*o4+0] = fmaf(f1, w.x, acc[1][4*o4+0]);
      acc[1][4*o4+1] = fmaf(f1, w.y, acc[1][4*o4+1]);
      acc[1][4*o4+2] = fmaf(f1, w.z, acc[1][4*o4+2]);
      acc[1][4*o4+3] = fmaf(f1, w.w, acc[1][4*o4+3]);
      acc[2][4*o4+0] = fmaf(f2, w.x, acc[2][4*o4+0]);
      acc[2][4*o4+1] = fmaf(f2, w.y, acc[2][4*o4+1]);
      acc[2][4*o4+2] = fmaf(f2, w.z, acc[2][4*o4+2]);
      acc[2][4*o4+3] = fmaf(f2, w.w, acc[2][4*o4+3]);
      acc[3][4*o4+0] = fmaf(f3, w.x, acc[3][4*o4+0]);
      acc[3][4*o4+1] = fmaf(f3, w.y, acc[3][4*o4+1]);
      acc[3][4*o4+2] = fmaf(f3, w.z, acc[3][4*o4+2]);
      acc[3][4*o4+3] = fmaf(f3, w.w, acc[3][4*o4+3]);
    }
  }
  const float* xb = x + (size_t)b * NC * NHW;
  float* ob = out + (size_t)b * NC * NHW;
#pragma unroll
  for (int o = 0; o < 16; o++) {
    size_t rowoff = (size_t)(ocbase + o) * NHW + n0;
#pragma unroll
    for (int r = 0; r < 4; r++)
      ob[rowoff + r * 256] = g * acc[r][o] + xb[rowoff + r * 256];
  }
}

extern "C" void kernel_launch(void* const* d_in, const int* in_sizes, int n_in,
                              void* d_out, int out_size, void* d_ws, size_t ws_size,
                              hipStream_t stream) {
  const float* x     = (const float*)d_in[0];
  const float* wq    = (const float*)d_in[1];
  const float* bq    = (const float*)d_in[2];
  const float* wk    = (const float*)d_in[3];
  const float* bk    = (const float*)d_in[4];
  const float* wv    = (const float*)d_in[5];
  const float* bv    = (const float*)d_in[6];
  const float* wa    = (const float*)d_in[7];
  const float* ba    = (const float*)d_in[8];
  const float* gamma = (const float*)d_in[9];
  float* out = (float*)d_out;

  float* ws   = (float*)d_ws;
  float* xp   = ws;                                  // NB*NC*NHWP   = 2,097,152
  float* q    = xp  + (size_t)NB * NC  * NHWP;       // NB*NCQ*NHW   = 1,048,576
  float* kT   = q   + (size_t)NB * NCQ * NHW;        // NB*NHWP*NCQ  =   262,144
  float* vT   = kT  + (size_t)NB * NHWP * NCQ;       // NB*NHWP*NCV  = 1,048,576
  float* feat = vT  + (size_t)NB * NHWP * NCV;       // NB*NCV*NHW   = 4,194,304
  // total 8,650,752 floats = 34.6 MB of ws

  pool_kernel  <<<NB * NC * NHWP / 256, 256, 0, stream>>>(x, xp);
  projq_kernel <<<NB * (NHW / 256),     256, 0, stream>>>(x, wq, bq, q);
  projkv_kernel<<<NB * (NHWP / 256),    256, 0, stream>>>(xp, wk, bk, wv, bv, kT, vT);
  attn_kernel  <<<NB * (NHW / 64),      256, 0, stream>>>(q, kT, vT, feat);
  outproj_kernel<<<NB * 32,             256, 0, stream>>>(feat, wa, ba, gamma, x, out);
}

// Round 2
// 185.284 us; speedup vs baseline: 12.6668x; 12.6668x over previous
//
#include <hip/hip_runtime.h>
#include <math.h>

#define NB 16
#define NC 128
#define NHW 4096     // 64*64
#define NHWP 1024    // 32*32
#define NCQ 16       // C/8
#define NCV 64       // C/2

typedef __attribute__((ext_vector_type(8))) short short8;
typedef __attribute__((ext_vector_type(4))) float f32x4;

__device__ inline unsigned short f2bf(float f) {
  unsigned u = __builtin_bit_cast(unsigned, f);
  u += 0x7fffu + ((u >> 16) & 1u);          // RNE
  return (unsigned short)(u >> 16);
}

// ------------------------------------------------ q = wq @ x  -> bf16 [b][n][16]
__global__ __launch_bounds__(256) void projq_kernel(const float* __restrict__ x,
    const float* __restrict__ wq, const float* __restrict__ bq,
    unsigned short* __restrict__ qT) {
  __shared__ float swT[NC][NCQ];   // swT[c][o] = wq[o][c]
  __shared__ float sb[NCQ];
  int tid = threadIdx.x;
  for (int i = tid; i < NC * NCQ; i += 256) {
    int o = i >> 7, c = i & 127;
    swT[c][o] = wq[i];
  }
  if (tid < NCQ) sb[tid] = bq[tid];
  __syncthreads();
  int b = blockIdx.x >> 4;
  int n = ((blockIdx.x & 15) << 8) | tid;
  const float* xb = x + (size_t)b * NC * NHW + n;
  float acc[NCQ];
#pragma unroll
  for (int o = 0; o < NCQ; o++) acc[o] = sb[o];
  for (int c = 0; c < NC; c++) {
    float xv = xb[(size_t)c * NHW];
    const float4* wr = (const float4*)&swT[c][0];
#pragma unroll
    for (int o4 = 0; o4 < NCQ / 4; o4++) {
      float4 w = wr[o4];
      acc[4*o4+0] = fmaf(xv, w.x, acc[4*o4+0]);
      acc[4*o4+1] = fmaf(xv, w.y, acc[4*o4+1]);
      acc[4*o4+2] = fmaf(xv, w.z, acc[4*o4+2]);
      acc[4*o4+3] = fmaf(xv, w.w, acc[4*o4+3]);
    }
  }
  unsigned short* qr = qT + ((size_t)b * NHW + n) * NCQ;
  short8 o0, o1;
#pragma unroll
  for (int o = 0; o < 8; o++) o0[o] = (short)f2bf(acc[o]);
#pragma unroll
  for (int o = 0; o < 8; o++) o1[o] = (short)f2bf(acc[8 + o]);
  *(short8*)qr = o0;
  *(short8*)(qr + 8) = o1;
}

// ---------------- fused pool + k,v proj: kT bf16 [b][m][16], v bf16 [b][c][m]
__global__ __launch_bounds__(256) void projkv_kernel(const float* __restrict__ x,
    const float* __restrict__ wk, const float* __restrict__ bk,
    const float* __restrict__ wv, const float* __restrict__ bv,
    unsigned short* __restrict__ kT, unsigned short* __restrict__ vv) {
  __shared__ float swkT[NC][NCQ];   // [c][o]
  __shared__ float swvT[NC][NCV];   // [c][o]
  __shared__ float sbk[NCQ];
  __shared__ float sbv[NCV];
  int tid = threadIdx.x;
  for (int i = tid; i < NC * NCQ; i += 256) {
    int o = i >> 7, c = i & 127;
    swkT[c][o] = wk[i];
  }
  for (int i = tid; i < NC * NCV; i += 256) {
    int o = i >> 7, c = i & 127;
    swvT[c][o] = wv[i];
  }
  if (tid < NCQ) sbk[tid] = bk[tid];
  if (tid < NCV) sbv[tid] = bv[tid];
  __syncthreads();
  int b = blockIdx.x >> 2;
  int m = ((blockIdx.x & 3) << 8) | tid;
  int j = m & 31, i2 = (m >> 5) & 31;
  const float* xb = x + (size_t)b * NC * NHW + (size_t)(2 * i2) * 64 + 2 * j;
  float ak[NCQ], av[NCV];
#pragma unroll
  for (int o = 0; o < NCQ; o++) ak[o] = sbk[o];
#pragma unroll
  for (int o = 0; o < NCV; o++) av[o] = sbv[o];
  for (int c = 0; c < NC; c++) {
    const float* xc = xb + (size_t)c * NHW;
    float2 t0 = *(const float2*)xc;
    float2 t1 = *(const float2*)(xc + 64);
    float xv = fmaxf(fmaxf(t0.x, t0.y), fmaxf(t1.x, t1.y));   // 2x2 maxpool
    const float4* wkr = (const float4*)&swkT[c][0];
#pragma unroll
    for (int o4 = 0; o4 < NCQ / 4; o4++) {
      float4 w = wkr[o4];
      ak[4*o4+0] = fmaf(xv, w.x, ak[4*o4+0]);
      ak[4*o4+1] = fmaf(xv, w.y, ak[4*o4+1]);
      ak[4*o4+2] = fmaf(xv, w.z, ak[4*o4+2]);
      ak[4*o4+3] = fmaf(xv, w.w, ak[4*o4+3]);
    }
    const float4* wvr = (const float4*)&swvT[c][0];
#pragma unroll
    for (int o4 = 0; o4 < NCV / 4; o4++) {
      float4 w = wvr[o4];
      av[4*o4+0] = fmaf(xv, w.x, av[4*o4+0]);
      av[4*o4+1] = fmaf(xv, w.y, av[4*o4+1]);
      av[4*o4+2] = fmaf(xv, w.z, av[4*o4+2]);
      av[4*o4+3] = fmaf(xv, w.w, av[4*o4+3]);
    }
  }
  unsigned short* kr = kT + ((size_t)b * NHWP + m) * NCQ;
  short8 k0, k1;
#pragma unroll
  for (int o = 0; o < 8; o++) k0[o] = (short)f2bf(ak[o]);
#pragma unroll
  for (int o = 0; o < 8; o++) k1[o] = (short)f2bf(ak[8 + o]);
  *(short8*)kr = k0;
  *(short8*)(kr + 8) = k1;
  unsigned short* vr = vv + (size_t)b * NCV * NHWP + m;
#pragma unroll
  for (int c = 0; c < NCV; c++) vr[(size_t)c * NHWP] = f2bf(av[c]);
}

// ------------- MFMA attention: S^T = K.Q^T (swapped), exp, PV via feat^T = V^T.P^T
// per wave: one 16-n tile, loop m in steps of 32. feat fp32 [b][c][n].
__global__ __launch_bounds__(256) void attn_kernel(const unsigned short* __restrict__ qT,
    const unsigned short* __restrict__ kT, const unsigned short* __restrict__ vv,
    float* __restrict__ feat) {
  int tid = threadIdx.x;
  int w   = tid >> 6;          // wave in block
  int l   = tid & 63;
  int g   = l >> 4;            // lane group 0..3
  int n16 = l & 15;
  int b   = blockIdx.x >> 6;
  int n0  = ((blockIdx.x & 63) << 6) + 16 * w;

  const unsigned short* qb = qT + (size_t)b * NHW * NCQ;
  const unsigned short* kb = kT + (size_t)b * NHWP * NCQ;
  const unsigned short* vb = vv + (size_t)b * NCV * NHWP;

  short8 zf = {0, 0, 0, 0, 0, 0, 0, 0};
  // B-frag Q^T [32c x 16n]: lane col n=l&15, rows c=8g+j (c>=16 zero-padded)
  short8 qf = zf;
  if (g < 2) qf = *(const short8*)&qb[(size_t)(n0 + n16) * NCQ + 8 * g];

  f32x4 facc[4];
#pragma unroll
  for (int k = 0; k < 4; k++) facc[k] = (f32x4){0.f, 0.f, 0.f, 0.f};
  float esum = 0.f;
  // sigma0 row remap so score D regs are exactly the PV B-frag k-order
  int mr = 8 * (n16 >> 2) + (n16 & 3);

  for (int m0 = 0; m0 < NHWP; m0 += 32) {
    short8 a0 = zf, a1 = zf;
    if (g < 2) {
      a0 = *(const short8*)&kb[(size_t)(m0 + mr) * NCQ + 8 * g];
      a1 = *(const short8*)&kb[(size_t)(m0 + mr + 4) * NCQ + 8 * g];
    }
    f32x4 z = {0.f, 0.f, 0.f, 0.f};
    f32x4 s0 = __builtin_amdgcn_mfma_f32_16x16x32_bf16(a0, qf, z, 0, 0, 0);
    f32x4 s1 = __builtin_amdgcn_mfma_f32_16x16x32_bf16(a1, qf, z, 0, 0, 0);
    short8 pt;
#pragma unroll
    for (int r = 0; r < 4; r++) {
      float e = __expf(s0[r]);
      esum += e;
      pt[r] = (short)f2bf(e);
    }
#pragma unroll
    for (int r = 0; r < 4; r++) {
      float e = __expf(s1[r]);
      esum += e;
      pt[4 + r] = (short)f2bf(e);
    }
    // PV: feat^T[c' x n] += V^T[c' x 32m] . P^T[32m x 16n]
#pragma unroll
    for (int k = 0; k < 4; k++) {
      short8 vf = *(const short8*)&vb[(size_t)(16 * k + n16) * NHWP + m0 + 8 * g];
      facc[k] = __builtin_amdgcn_mfma_f32_16x16x32_bf16(vf, pt, facc[k], 0, 0, 0);
    }
  }
  esum += __shfl_xor(esum, 16);
  esum += __shfl_xor(esum, 32);
  float inv = 1.0f / esum;
  float* fb = feat + (size_t)b * NCV * NHW + n0 + n16;
#pragma unroll
  for (int k = 0; k < 4; k++)
#pragma unroll
    for (int r = 0; r < 4; r++)
      fb[(size_t)(16 * k + 4 * g + r) * NHW] = facc[k][r] * inv;
}

// -------------------------------------- out = gamma*(wa@feat + ba) + x
__global__ __launch_bounds__(256) void outproj_kernel(const float* __restrict__ feat,
    const float* __restrict__ wa, const float* __restrict__ ba,
    const float* __restrict__ gamma, const float* __restrict__ x,
    float* __restrict__ out) {
  __shared__ float swaT[NCV][16];   // swaT[c][o] = wa[ocbase+o][c]
  __shared__ float sba[16];
  int tid  = threadIdx.x;
  int ocg  = blockIdx.x & 7;
  int tile = (blockIdx.x >> 3) & 3;
  int b    = blockIdx.x >> 5;
  int ocbase = ocg * 16;
  for (int i = tid; i < NCV * 16; i += 256) {
    int c = i >> 4, o = i & 15;
    swaT[c][o] = wa[(size_t)(ocbase + o) * NCV + c];
  }
  if (tid < 16) sba[tid] = ba[ocbase + tid];
  __syncthreads();
  float g = gamma[0];
  int n0 = tile * 1024 + tid;
  const float* fb = feat + (size_t)b * NCV * NHW;
  float acc[4][16];
#pragma unroll
  for (int r = 0; r < 4; r++)
#pragma unroll
    for (int o = 0; o < 16; o++) acc[r][o] = sba[o];
  for (int c = 0; c < NCV; c++) {
    const float* fr = fb + (size_t)c * NHW + n0;
    float f0 = fr[0], f1 = fr[256], f2 = fr[512], f3 = fr[768];
    const float4* wr = (const float4*)&swaT[c][0];
#pragma unroll
    for (int o4 = 0; o4 < 4; o4++) {
      float4 w = wr[o4];
      acc[0][4*o4+0] = fmaf(f0, w.x, acc[0][4*o4+0]);
      acc[0][4*o4+1] = fmaf(f0, w.y, acc[0][4*o4+1]);
      acc[0][4*o4+2] = fmaf(f0, w.z, acc[0][4*o4+2]);
      acc[0][4*o4+3] = fmaf(f0, w.w, acc[0][4*o4+3]);
      acc[1][4*o4+0] = fmaf(f1, w.x, acc[1][4*o4+0]);
      acc[1][4*o4+1] = fmaf(f1, w.y, acc[1][4*o4+1]);
      acc[1][4*o4+2] = fmaf(f1, w.z, acc[1][4*o4+2]);
      acc[1][4*o4+3] = fmaf(f1, w.w, acc[1][4*o4+3]);
      acc[2][4*o4+0] = fmaf(f2, w.x, acc[2][4*o4+0]);
      acc[2][4*o4+1] = fmaf(f2, w.y, acc[2][4*o4+1]);
      acc[2][4*o4+2] = fmaf(f2, w.z, acc[2][4*o4+2]);
      acc[2][4*o4+3] = fmaf(f2, w.w, acc[2][4*o4+3]);
      acc[3][4*o4+0] = fmaf(f3, w.x, acc[3][4*o4+0]);
      acc[3][4*o4+1] = fmaf(f3, w.y, acc[3][4*o4+1]);
      acc[3][4*o4+2] = fmaf(f3, w.z, acc[3][4*o4+2]);
      acc[3][4*o4+3] = fmaf(f3, w.w, acc[3][4*o4+3]);
    }
  }
  const float* xb = x + (size_t)b * NC * NHW;
  float* ob = out + (size_t)b * NC * NHW;
#pragma unroll
  for (int o = 0; o < 16; o++) {
    size_t rowoff = (size_t)(ocbase + o) * NHW + n0;
#pragma unroll
    for (int r = 0; r < 4; r++)
      ob[rowoff + r * 256] = g * acc[r][o] + xb[rowoff + r * 256];
  }
}

extern "C" void kernel_launch(void* const* d_in, const int* in_sizes, int n_in,
                              void* d_out, int out_size, void* d_ws, size_t ws_size,
                              hipStream_t stream) {
  const float* x     = (const float*)d_in[0];
  const float* wq    = (const float*)d_in[1];
  const float* bq    = (const float*)d_in[2];
  const float* wk    = (const float*)d_in[3];
  const float* bk    = (const float*)d_in[4];
  const float* wv    = (const float*)d_in[5];
  const float* bv    = (const float*)d_in[6];
  const float* wa    = (const float*)d_in[7];
  const float* ba    = (const float*)d_in[8];
  const float* gamma = (const float*)d_in[9];
  float* out = (float*)d_out;

  unsigned short* qT = (unsigned short*)d_ws;                  // 16*4096*16 ush = 2 MB
  unsigned short* kT = qT + (size_t)NB * NHW * NCQ;            // 16*1024*16 ush = 0.5 MB
  unsigned short* vv = kT + (size_t)NB * NHWP * NCQ;           // 16*64*1024 ush = 2 MB
  float*         feat = (float*)(vv + (size_t)NB * NCV * NHWP);// 16*64*4096 f32 = 16.8 MB

  projq_kernel  <<<NB * (NHW / 256),  256, 0, stream>>>(x, wq, bq, qT);
  projkv_kernel <<<NB * (NHWP / 256), 256, 0, stream>>>(x, wk, bk, wv, bv, kT, vv);
  attn_kernel   <<<NB * (NHW / 64),   256, 0, stream>>>(qT, kT, vv, feat);
  outproj_kernel<<<NB * 32,           256, 0, stream>>>(feat, wa, ba, gamma, x, out);
}

// Round 3
// 95.142 us; speedup vs baseline: 24.6679x; 1.9474x over previous
//
#include <hip/hip_runtime.h>
#include <math.h>

#define NB 16
#define NC 128
#define NHW 4096     // 64*64
#define NHWP 1024    // 32*32
#define NCQ 16       // C/8
#define NCV 64       // C/2

typedef __attribute__((ext_vector_type(8))) short short8;
typedef __attribute__((ext_vector_type(4))) float f32x4;

__device__ inline unsigned short f2bf(float f) {
  unsigned u = __builtin_bit_cast(unsigned, f);
  u += 0x7fffu + ((u >> 16) & 1u);          // RNE
  return (unsigned short)(u >> 16);
}

__device__ inline unsigned pk2(float lo, float hi) {
  unsigned r;
  asm("v_cvt_pk_bf16_f32 %0, %1, %2" : "=v"(r) : "v"(lo), "v"(hi));
  return r;
}

// ---------------- fused pool + k,v proj, og-split (5) x cg-split (2)
// outputs: kT bf16 [b][m][16], vv bf16 [b][c][m]
__global__ __launch_bounds__(256) void projkv_kernel(const float* __restrict__ x,
    const float* __restrict__ wk, const float* __restrict__ bk,
    const float* __restrict__ wv, const float* __restrict__ bv,
    unsigned short* __restrict__ kT, unsigned short* __restrict__ vv) {
  __shared__ float swT[NC][16];     // swT[c][o]
  __shared__ float pacc[128][17];   // cg1 partials, padded
  __shared__ float sbias[16];
  int tid = threadIdx.x;
  int og = blockIdx.x % 5;
  int mt = (blockIdx.x / 5) & 7;
  int b  = blockIdx.x / 40;
  const float* wsrc = (og == 0) ? wk : (wv + (size_t)(og - 1) * 16 * NC);
  const float* bsrc = (og == 0) ? bk : (bv + (og - 1) * 16);
  for (int i = tid; i < NC * 16; i += 256) {
    int o = i >> 7, c = i & 127;
    swT[c][o] = wsrc[i];
  }
  if (tid < 16) sbias[tid] = bsrc[tid];
  __syncthreads();
  int ml = tid & 127, cg = tid >> 7;
  int m = mt * 128 + ml;
  int j = m & 31, i2 = m >> 5;
  const float* xb = x + (size_t)b * NC * NHW + (size_t)(2 * i2) * 64 + 2 * j
                      + (size_t)cg * 64 * NHW;
  float acc[16];
#pragma unroll
  for (int o = 0; o < 16; o++) acc[o] = 0.f;
#pragma unroll 4
  for (int ci = 0; ci < 64; ci++) {
    int c = cg * 64 + ci;
    const float* xc = xb + (size_t)ci * NHW;
    float2 t0 = *(const float2*)xc;
    float2 t1 = *(const float2*)(xc + 64);
    float xv = fmaxf(fmaxf(t0.x, t0.y), fmaxf(t1.x, t1.y));   // 2x2 maxpool
    const float4* wr = (const float4*)&swT[c][0];
#pragma unroll
    for (int o4 = 0; o4 < 4; o4++) {
      float4 w4 = wr[o4];
      acc[4*o4+0] = fmaf(xv, w4.x, acc[4*o4+0]);
      acc[4*o4+1] = fmaf(xv, w4.y, acc[4*o4+1]);
      acc[4*o4+2] = fmaf(xv, w4.z, acc[4*o4+2]);
      acc[4*o4+3] = fmaf(xv, w4.w, acc[4*o4+3]);
    }
  }
  if (cg == 1) {
#pragma unroll
    for (int o = 0; o < 16; o++) pacc[ml][o] = acc[o];
  }
  __syncthreads();
  if (cg == 0) {
#pragma unroll
    for (int o = 0; o < 16; o++) acc[o] += pacc[ml][o] + sbias[o];
    if (og == 0) {
      unsigned short* kr = kT + ((size_t)b * NHWP + m) * NCQ;
      uint4 u0, u1;
      u0.x = pk2(acc[0],  acc[1]);  u0.y = pk2(acc[2],  acc[3]);
      u0.z = pk2(acc[4],  acc[5]);  u0.w = pk2(acc[6],  acc[7]);
      u1.x = pk2(acc[8],  acc[9]);  u1.y = pk2(acc[10], acc[11]);
      u1.z = pk2(acc[12], acc[13]); u1.w = pk2(acc[14], acc[15]);
      *(uint4*)kr = u0;
      *(uint4*)(kr + 8) = u1;
    } else {
      unsigned short* vr = vv + (size_t)b * NCV * NHWP + (size_t)(og - 1) * 16 * NHWP + m;
#pragma unroll
      for (int o = 0; o < 16; o++) vr[(size_t)o * NHWP] = f2bf(acc[o]);
    }
  }
}

// ------------- MFMA attention, fused Q-proj, 32n/wave, m split across 4 waves
// featT bf16 [b][n][64]
__global__ __launch_bounds__(256) void attn_kernel(const float* __restrict__ x,
    const float* __restrict__ wq, const float* __restrict__ bq,
    const unsigned short* __restrict__ kT, const unsigned short* __restrict__ vv,
    unsigned short* __restrict__ featT) {
  __shared__ unsigned short qlds[32][16];   // Q^T as [n][c] bf16
  __shared__ float sfacc[4][64][35];        // per-wave facc(32) + esumA/B
  int tid = threadIdx.x;
  int w = tid >> 6, l = tid & 63, g = l >> 4, n16 = l & 15;
  int b  = blockIdx.x >> 7;                 // 16 b x 128 ntiles
  int n0 = (blockIdx.x & 127) << 5;         // 32 n per block

  // ---- fused Q projection: waves 0,1 compute Q^T[16c x 16n] for their n-half
  if (w < 2) {
    f32x4 qacc;
#pragma unroll
    for (int r = 0; r < 4; r++) qacc[r] = bq[4 * g + r];
#pragma unroll
    for (int s = 0; s < 4; s++) {
      const float* wr = wq + n16 * NC + 32 * s + 8 * g;
      float4 wa0 = *(const float4*)wr;
      float4 wa1 = *(const float4*)(wr + 4);
      union { short8 s8; uint4 u4; } af;
      af.u4.x = pk2(wa0.x, wa0.y); af.u4.y = pk2(wa0.z, wa0.w);
      af.u4.z = pk2(wa1.x, wa1.y); af.u4.w = pk2(wa1.z, wa1.w);
      const float* xc = x + ((size_t)b * NC + 32 * s + 8 * g) * NHW + n0 + 16 * w + n16;
      float xv[8];
#pragma unroll
      for (int jj = 0; jj < 8; jj++) xv[jj] = xc[(size_t)jj * NHW];
      union { short8 s8; uint4 u4; } bf_;
      bf_.u4.x = pk2(xv[0], xv[1]); bf_.u4.y = pk2(xv[2], xv[3]);
      bf_.u4.z = pk2(xv[4], xv[5]); bf_.u4.w = pk2(xv[6], xv[7]);
      qacc = __builtin_amdgcn_mfma_f32_16x16x32_bf16(af.s8, bf_.s8, qacc, 0, 0, 0);
    }
    // D lane(g,n16): rows co=4g+r, col n16 -> qlds[16w+n16][4g+r]
    unsigned* qw = (unsigned*)&qlds[16 * w + n16][4 * g];
    qw[0] = pk2(qacc[0], qacc[1]);
    qw[1] = pk2(qacc[2], qacc[3]);
  }
  __syncthreads();

  short8 zf = {0, 0, 0, 0, 0, 0, 0, 0};
  short8 qfA = zf, qfB = zf;
  if (g < 2) {
    qfA = *(const short8*)&qlds[n16][8 * g];
    qfB = *(const short8*)&qlds[16 + n16][8 * g];
  }

  const unsigned short* kb = kT + (size_t)b * NHWP * NCQ;
  const unsigned short* vb = vv + (size_t)b * NCV * NHWP;
  f32x4 faccA[4], faccB[4];
#pragma unroll
  for (int kt = 0; kt < 4; kt++) {
    faccA[kt] = (f32x4){0.f, 0.f, 0.f, 0.f};
    faccB[kt] = (f32x4){0.f, 0.f, 0.f, 0.f};
  }
  float esA = 0.f, esB = 0.f;
  int mr = 8 * (n16 >> 2) + (n16 & 3);      // sigma remap
  int mbase = w << 8;                       // wave's 256-m slice

#pragma unroll 2
  for (int mi = 0; mi < 8; mi++) {
    int m0 = mbase + 32 * mi;
    short8 a0 = zf, a1 = zf;
    if (g < 2) {
      a0 = *(const short8*)&kb[(size_t)(m0 + mr) * NCQ + 8 * g];
      a1 = *(const short8*)&kb[(size_t)(m0 + mr + 4) * NCQ + 8 * g];
    }
    f32x4 z = {0.f, 0.f, 0.f, 0.f};
    f32x4 s0A = __builtin_amdgcn_mfma_f32_16x16x32_bf16(a0, qfA, z, 0, 0, 0);
    f32x4 s1A = __builtin_amdgcn_mfma_f32_16x16x32_bf16(a1, qfA, z, 0, 0, 0);
    f32x4 s0B = __builtin_amdgcn_mfma_f32_16x16x32_bf16(a0, qfB, z, 0, 0, 0);
    f32x4 s1B = __builtin_amdgcn_mfma_f32_16x16x32_bf16(a1, qfB, z, 0, 0, 0);
    float eA0 = __expf(s0A[0]), eA1 = __expf(s0A[1]), eA2 = __expf(s0A[2]), eA3 = __expf(s0A[3]);
    float eA4 = __expf(s1A[0]), eA5 = __expf(s1A[1]), eA6 = __expf(s1A[2]), eA7 = __expf(s1A[3]);
    float eB0 = __expf(s0B[0]), eB1 = __expf(s0B[1]), eB2 = __expf(s0B[2]), eB3 = __expf(s0B[3]);
    float eB4 = __expf(s1B[0]), eB5 = __expf(s1B[1]), eB6 = __expf(s1B[2]), eB7 = __expf(s1B[3]);
    esA += (eA0 + eA1) + (eA2 + eA3) + (eA4 + eA5) + (eA6 + eA7);
    esB += (eB0 + eB1) + (eB2 + eB3) + (eB4 + eB5) + (eB6 + eB7);
    union { short8 s8; uint4 u4; } ptA, ptB;
    ptA.u4.x = pk2(eA0, eA1); ptA.u4.y = pk2(eA2, eA3);
    ptA.u4.z = pk2(eA4, eA5); ptA.u4.w = pk2(eA6, eA7);
    ptB.u4.x = pk2(eB0, eB1); ptB.u4.y = pk2(eB2, eB3);
    ptB.u4.z = pk2(eB4, eB5); ptB.u4.w = pk2(eB6, eB7);
#pragma unroll
    for (int kt = 0; kt < 4; kt++) {
      short8 vf = *(const short8*)&vb[(size_t)(16 * kt + n16) * NHWP + m0 + 8 * g];
      faccA[kt] = __builtin_amdgcn_mfma_f32_16x16x32_bf16(vf, ptA.s8, faccA[kt], 0, 0, 0);
      faccB[kt] = __builtin_amdgcn_mfma_f32_16x16x32_bf16(vf, ptB.s8, faccB[kt], 0, 0, 0);
    }
  }

  // ---- cross-wave combine: every wave dumps, wave w sums c-tile kt=w
#pragma unroll
  for (int kt = 0; kt < 4; kt++)
#pragma unroll
    for (int r = 0; r < 4; r++) {
      sfacc[w][l][4 * kt + r]      = faccA[kt][r];
      sfacc[w][l][16 + 4 * kt + r] = faccB[kt][r];
    }
  sfacc[w][l][32] = esA;
  sfacc[w][l][33] = esB;
  __syncthreads();
  float fA[4], fB[4];
#pragma unroll
  for (int r = 0; r < 4; r++) { fA[r] = 0.f; fB[r] = 0.f; }
  float teA = 0.f, teB = 0.f;
#pragma unroll
  for (int wp = 0; wp < 4; wp++) {
#pragma unroll
    for (int r = 0; r < 4; r++) {
      fA[r] += sfacc[wp][l][4 * w + r];
      fB[r] += sfacc[wp][l][16 + 4 * w + r];
    }
    teA += sfacc[wp][l][32];
    teB += sfacc[wp][l][33];
  }
  teA += __shfl_xor(teA, 16); teA += __shfl_xor(teA, 32);
  teB += __shfl_xor(teB, 16); teB += __shfl_xor(teB, 32);
  float invA = 1.0f / teA, invB = 1.0f / teB;
  unsigned short* fra = featT + ((size_t)b * NHW + n0 + n16) * NCV + 16 * w + 4 * g;
  ((unsigned*)fra)[0] = pk2(fA[0] * invA, fA[1] * invA);
  ((unsigned*)fra)[1] = pk2(fA[2] * invA, fA[3] * invA);
  unsigned short* frb = featT + ((size_t)b * NHW + n0 + 16 + n16) * NCV + 16 * w + 4 * g;
  ((unsigned*)frb)[0] = pk2(fB[0] * invB, fB[1] * invB);
  ((unsigned*)frb)[1] = pk2(fB[2] * invB, fB[3] * invB);
}

// -------------------- out = gamma*(wa@feat + ba) + x  (MFMA, K=64)
__global__ __launch_bounds__(256) void outproj_kernel(const unsigned short* __restrict__ featT,
    const float* __restrict__ wa, const float* __restrict__ ba,
    const float* __restrict__ gamma, const float* __restrict__ x,
    float* __restrict__ out) {
  __shared__ unsigned short walds[NC][64];   // bf16, XOR-swizzled rows
  int tid = threadIdx.x;
  int w = tid >> 6, l = tid & 63, g = l >> 4, n16 = l & 15;
  int b  = blockIdx.x >> 6;
  int n0 = (blockIdx.x & 63) << 6;           // 64 n per block
  {
    int row = tid >> 1, ch = (tid & 1) * 32;
    const float* src = wa + (size_t)row * NCV + ch;
    int rx = (row & 7) << 4;
    char* base = (char*)&walds[0][0] + row * 128;
#pragma unroll
    for (int q = 0; q < 4; q++) {
      float4 f0 = *(const float4*)(src + 8 * q);
      float4 f1 = *(const float4*)(src + 8 * q + 4);
      uint4 pv;
      pv.x = pk2(f0.x, f0.y); pv.y = pk2(f0.z, f0.w);
      pv.z = pk2(f1.x, f1.y); pv.w = pk2(f1.z, f1.w);
      int colb = ch * 2 + q * 16;
      *(uint4*)(base + (colb ^ rx)) = pv;
    }
  }
  __syncthreads();

  // B-frags: featT[n][c], 8 chunks
  const unsigned short* fb = featT + ((size_t)b * NHW + n0 + n16) * NCV;
  short8 bfr[4][2];
#pragma unroll
  for (int nt = 0; nt < 4; nt++)
#pragma unroll
    for (int s = 0; s < 2; s++)
      bfr[nt][s] = *(const short8*)(fb + (size_t)nt * 16 * NCV + 32 * s + 8 * g);

  float g0 = gamma[0];
  f32x4 acc[2][4];
#pragma unroll
  for (int ti = 0; ti < 2; ti++) {
    int ot = 2 * w + ti;
    int row = 16 * ot + n16;
    char* abase = (char*)&walds[0][0] + row * 128;
    int rx = (row & 7) << 4;
    short8 af0 = *(const short8*)(abase + ((16 * g) ^ rx));
    short8 af1 = *(const short8*)(abase + ((64 + 16 * g) ^ rx));
    float b0 = ba[16 * ot + 4 * g + 0];
    float b1 = ba[16 * ot + 4 * g + 1];
    float b2 = ba[16 * ot + 4 * g + 2];
    float b3 = ba[16 * ot + 4 * g + 3];
#pragma unroll
    for (int nt = 0; nt < 4; nt++) {
      f32x4 c0 = {b0, b1, b2, b3};
      c0 = __builtin_amdgcn_mfma_f32_16x16x32_bf16(af0, bfr[nt][0], c0, 0, 0, 0);
      c0 = __builtin_amdgcn_mfma_f32_16x16x32_bf16(af1, bfr[nt][1], c0, 0, 0, 0);
      acc[ti][nt] = c0;
    }
  }
#pragma unroll
  for (int ti = 0; ti < 2; ti++) {
    int ot = 2 * w + ti;
#pragma unroll
    for (int nt = 0; nt < 4; nt++) {
#pragma unroll
      for (int r = 0; r < 4; r++) {
        size_t idx = ((size_t)b * NC + 16 * ot + 4 * g + r) * NHW + n0 + 16 * nt + n16;
        out[idx] = g0 * acc[ti][nt][r] + x[idx];
      }
    }
  }
}

extern "C" void kernel_launch(void* const* d_in, const int* in_sizes, int n_in,
                              void* d_out, int out_size, void* d_ws, size_t ws_size,
                              hipStream_t stream) {
  const float* x     = (const float*)d_in[0];
  const float* wq    = (const float*)d_in[1];
  const float* bq    = (const float*)d_in[2];
  const float* wk    = (const float*)d_in[3];
  const float* bk    = (const float*)d_in[4];
  const float* wv    = (const float*)d_in[5];
  const float* bv    = (const float*)d_in[6];
  const float* wa    = (const float*)d_in[7];
  const float* ba    = (const float*)d_in[8];
  const float* gamma = (const float*)d_in[9];
  float* out = (float*)d_out;

  unsigned short* kT    = (unsigned short*)d_ws;                 // 16*1024*16  = 512 KB
  unsigned short* vv    = kT + (size_t)NB * NHWP * NCQ;          // 16*64*1024  = 2 MB
  unsigned short* featT = vv + (size_t)NB * NCV * NHWP;          // 16*4096*64  = 8 MB

  projkv_kernel <<<NB * 5 * 8,   256, 0, stream>>>(x, wk, bk, wv, bv, kT, vv);
  attn_kernel   <<<NB * 128,     256, 0, stream>>>(x, wq, bq, kT, vv, featT);
  outproj_kernel<<<NB * 64,      256, 0, stream>>>(featT, wa, ba, gamma, x, out);
}

// Round 4
// 76.498 us; speedup vs baseline: 30.6800x; 1.2437x over previous
//
#include <hip/hip_runtime.h>
#include <math.h>

#define NB 16
#define NC 128
#define NHW 4096     // 64*64
#define NHWP 1024    // 32*32
#define NCQ 16       // C/8
#define NCV 64       // C/2
#define L2E 1.44269504f

typedef __attribute__((ext_vector_type(8))) short short8;
typedef __attribute__((ext_vector_type(4))) float f32x4;

__device__ inline unsigned short f2bf(float f) {
  unsigned u = __builtin_bit_cast(unsigned, f);
  u += 0x7fffu + ((u >> 16) & 1u);          // RNE
  return (unsigned short)(u >> 16);
}

__device__ inline unsigned pk2(float lo, float hi) {
  unsigned r;
  asm("v_cvt_pk_bf16_f32 %0, %1, %2" : "=v"(r) : "v"(lo), "v"(hi));
  return r;
}

// XCD-aware chunked swizzle (grids are multiples of 8)
__device__ inline int xcd_swz(int bid, int nwg) {
  int cpx = nwg >> 3;
  return (bid & 7) * cpx + (bid >> 3);
}

// ---------------- fused pool + k,v proj, og-split (5) x mt (16) x cg-split (4)
// outputs: kT bf16 [b][m][16], vv bf16 [b][c][m]
__global__ __launch_bounds__(256) void projkv_kernel(const float* __restrict__ x,
    const float* __restrict__ wk, const float* __restrict__ bk,
    const float* __restrict__ wv, const float* __restrict__ bv,
    unsigned short* __restrict__ kT, unsigned short* __restrict__ vv) {
  __shared__ float swT[NC][16];     // swT[c][o]
  __shared__ float pacc[3][64][17]; // cg 1..3 partials
  __shared__ float sbias[16];
  int lbid = xcd_swz(blockIdx.x, NB * 5 * 16);
  int tid = threadIdx.x;
  int og = lbid % 5;
  int mt = (lbid / 5) & 15;
  int b  = lbid / 80;
  const float* wsrc = (og == 0) ? wk : (wv + (size_t)(og - 1) * 16 * NC);
  const float* bsrc = (og == 0) ? bk : (bv + (og - 1) * 16);
  for (int i = tid; i < NC * 16; i += 256) {
    int o = i >> 7, c = i & 127;
    swT[c][o] = wsrc[i];
  }
  if (tid < 16) sbias[tid] = bsrc[tid];
  __syncthreads();
  int ml = tid & 63, cg = tid >> 6;
  int m = mt * 64 + ml;
  int j = m & 31, i2 = m >> 5;
  const float* xb = x + ((size_t)b * NC + cg * 32) * NHW + (size_t)(2 * i2) * 64 + 2 * j;
  float acc[16];
#pragma unroll
  for (int o = 0; o < 16; o++) acc[o] = 0.f;
#pragma unroll 4
  for (int ci = 0; ci < 32; ci++) {
    int c = cg * 32 + ci;
    const float* xc = xb + (size_t)ci * NHW;
    float2 t0 = *(const float2*)xc;
    float2 t1 = *(const float2*)(xc + 64);
    float xv = fmaxf(fmaxf(t0.x, t0.y), fmaxf(t1.x, t1.y));   // 2x2 maxpool
    const float4* wr = (const float4*)&swT[c][0];
#pragma unroll
    for (int o4 = 0; o4 < 4; o4++) {
      float4 w4 = wr[o4];
      acc[4*o4+0] = fmaf(xv, w4.x, acc[4*o4+0]);
      acc[4*o4+1] = fmaf(xv, w4.y, acc[4*o4+1]);
      acc[4*o4+2] = fmaf(xv, w4.z, acc[4*o4+2]);
      acc[4*o4+3] = fmaf(xv, w4.w, acc[4*o4+3]);
    }
  }
  if (cg > 0) {
#pragma unroll
    for (int o = 0; o < 16; o++) pacc[cg - 1][ml][o] = acc[o];
  }
  __syncthreads();
  if (cg == 0) {
#pragma unroll
    for (int o = 0; o < 16; o++)
      acc[o] += pacc[0][ml][o] + pacc[1][ml][o] + pacc[2][ml][o] + sbias[o];
    if (og == 0) {
      unsigned short* kr = kT + ((size_t)b * NHWP + m) * NCQ;
      uint4 u0, u1;
      u0.x = pk2(acc[0],  acc[1]);  u0.y = pk2(acc[2],  acc[3]);
      u0.z = pk2(acc[4],  acc[5]);  u0.w = pk2(acc[6],  acc[7]);
      u1.x = pk2(acc[8],  acc[9]);  u1.y = pk2(acc[10], acc[11]);
      u1.z = pk2(acc[12], acc[13]); u1.w = pk2(acc[14], acc[15]);
      *(uint4*)kr = u0;
      *(uint4*)(kr + 8) = u1;
    } else {
      unsigned short* vr = vv + (size_t)b * NCV * NHWP + (size_t)(og - 1) * 16 * NHWP + m;
#pragma unroll
      for (int o = 0; o < 16; o++) vr[(size_t)o * NHWP] = f2bf(acc[o]);
    }
  }
}

// ------------- MFMA attention: fused Q-proj (all waves), 32n x 512m per wave,
// m-split 2 with LDS pair-combine; esum via ones-MFMA; featT bf16 [b][n][64]
__global__ __launch_bounds__(256) void attn_kernel(const float* __restrict__ x,
    const float* __restrict__ wq, const float* __restrict__ bq,
    const unsigned short* __restrict__ kT, const unsigned short* __restrict__ vv,
    unsigned short* __restrict__ featT) {
  __shared__ unsigned short qlds[64][16];   // Q^T as [n][c] bf16 (log2e-scaled)
  __shared__ float sfacc[2][64][36];        // mh=1 partials: 32 facc + 2 esum
  int tid = threadIdx.x;
  int w = tid >> 6, l = tid & 63, g = l >> 4, n16 = l & 15;
  int nh = w & 1, mh = w >> 1;
  int lbid = xcd_swz(blockIdx.x, NB * 64);
  int b  = lbid >> 6;
  int n0 = (lbid & 63) << 6;                // 64 n per block

  // ---- fused Q projection: wave w computes Q^T[16c x 16n] tile w, x log2(e)
  {
    f32x4 qacc;
#pragma unroll
    for (int r = 0; r < 4; r++) qacc[r] = bq[4 * g + r] * L2E;
#pragma unroll
    for (int s = 0; s < 4; s++) {
      const float* wr = wq + n16 * NC + 32 * s + 8 * g;
      float4 wa0 = *(const float4*)wr;
      float4 wa1 = *(const float4*)(wr + 4);
      union { short8 s8; uint4 u4; } af;
      af.u4.x = pk2(wa0.x * L2E, wa0.y * L2E); af.u4.y = pk2(wa0.z * L2E, wa0.w * L2E);
      af.u4.z = pk2(wa1.x * L2E, wa1.y * L2E); af.u4.w = pk2(wa1.z * L2E, wa1.w * L2E);
      const float* xc = x + ((size_t)b * NC + 32 * s + 8 * g) * NHW + n0 + 16 * w + n16;
      float xv[8];
#pragma unroll
      for (int jj = 0; jj < 8; jj++) xv[jj] = xc[(size_t)jj * NHW];
      union { short8 s8; uint4 u4; } bf_;
      bf_.u4.x = pk2(xv[0], xv[1]); bf_.u4.y = pk2(xv[2], xv[3]);
      bf_.u4.z = pk2(xv[4], xv[5]); bf_.u4.w = pk2(xv[6], xv[7]);
      qacc = __builtin_amdgcn_mfma_f32_16x16x32_bf16(af.s8, bf_.s8, qacc, 0, 0, 0);
    }
    unsigned* qw = (unsigned*)&qlds[16 * w + n16][4 * g];
    qw[0] = pk2(qacc[0], qacc[1]);
    qw[1] = pk2(qacc[2], qacc[3]);
  }
  __syncthreads();

  short8 zf = {0, 0, 0, 0, 0, 0, 0, 0};
  short8 qfA = zf, qfB = zf;
  if (g < 2) {
    qfA = *(const short8*)&qlds[32 * nh + n16][8 * g];
    qfB = *(const short8*)&qlds[32 * nh + 16 + n16][8 * g];
  }
  short8 ones;
#pragma unroll
  for (int jj = 0; jj < 8; jj++) ones[jj] = (short)0x3F80;

  const unsigned short* kb = kT + (size_t)b * NHWP * NCQ;
  const unsigned short* vb = vv + (size_t)b * NCV * NHWP;
  f32x4 faccA[4], faccB[4];
#pragma unroll
  for (int kt = 0; kt < 4; kt++) {
    faccA[kt] = (f32x4){0.f, 0.f, 0.f, 0.f};
    faccB[kt] = (f32x4){0.f, 0.f, 0.f, 0.f};
  }
  f32x4 esA4 = {0.f, 0.f, 0.f, 0.f}, esB4 = {0.f, 0.f, 0.f, 0.f};
  int mr = 8 * (n16 >> 2) + (n16 & 3);      // sigma remap
  int mbase = mh << 9;                      // wave pair's 512-m half

#pragma unroll 2
  for (int mi = 0; mi < 16; mi++) {
    int m0 = mbase + 32 * mi;
    short8 a0 = zf, a1 = zf;
    if (g < 2) {
      a0 = *(const short8*)&kb[(size_t)(m0 + mr) * NCQ + 8 * g];
      a1 = *(const short8*)&kb[(size_t)(m0 + mr + 4) * NCQ + 8 * g];
    }
    f32x4 z = {0.f, 0.f, 0.f, 0.f};
    f32x4 s0A = __builtin_amdgcn_mfma_f32_16x16x32_bf16(a0, qfA, z, 0, 0, 0);
    f32x4 s1A = __builtin_amdgcn_mfma_f32_16x16x32_bf16(a1, qfA, z, 0, 0, 0);
    f32x4 s0B = __builtin_amdgcn_mfma_f32_16x16x32_bf16(a0, qfB, z, 0, 0, 0);
    f32x4 s1B = __builtin_amdgcn_mfma_f32_16x16x32_bf16(a1, qfB, z, 0, 0, 0);
    // scores are log2e-scaled -> plain exp2
    float eA0 = __builtin_amdgcn_exp2f(s0A[0]), eA1 = __builtin_amdgcn_exp2f(s0A[1]);
    float eA2 = __builtin_amdgcn_exp2f(s0A[2]), eA3 = __builtin_amdgcn_exp2f(s0A[3]);
    float eA4 = __builtin_amdgcn_exp2f(s1A[0]), eA5 = __builtin_amdgcn_exp2f(s1A[1]);
    float eA6 = __builtin_amdgcn_exp2f(s1A[2]), eA7 = __builtin_amdgcn_exp2f(s1A[3]);
    float eB0 = __builtin_amdgcn_exp2f(s0B[0]), eB1 = __builtin_amdgcn_exp2f(s0B[1]);
    float eB2 = __builtin_amdgcn_exp2f(s0B[2]), eB3 = __builtin_amdgcn_exp2f(s0B[3]);
    float eB4 = __builtin_amdgcn_exp2f(s1B[0]), eB5 = __builtin_amdgcn_exp2f(s1B[1]);
    float eB6 = __builtin_amdgcn_exp2f(s1B[2]), eB7 = __builtin_amdgcn_exp2f(s1B[3]);
    union { short8 s8; uint4 u4; } ptA, ptB;
    ptA.u4.x = pk2(eA0, eA1); ptA.u4.y = pk2(eA2, eA3);
    ptA.u4.z = pk2(eA4, eA5); ptA.u4.w = pk2(eA6, eA7);
    ptB.u4.x = pk2(eB0, eB1); ptB.u4.y = pk2(eB2, eB3);
    ptB.u4.z = pk2(eB4, eB5); ptB.u4.w = pk2(eB6, eB7);
    // esum via ones-row MFMA (colsum of P^T) -- keeps VALU free
    esA4 = __builtin_amdgcn_mfma_f32_16x16x32_bf16(ones, ptA.s8, esA4, 0, 0, 0);
    esB4 = __builtin_amdgcn_mfma_f32_16x16x32_bf16(ones, ptB.s8, esB4, 0, 0, 0);
#pragma unroll
    for (int kt = 0; kt < 4; kt++) {
      short8 vf = *(const short8*)&vb[(size_t)(16 * kt + n16) * NHWP + m0 + 8 * g];
      faccA[kt] = __builtin_amdgcn_mfma_f32_16x16x32_bf16(vf, ptA.s8, faccA[kt], 0, 0, 0);
      faccB[kt] = __builtin_amdgcn_mfma_f32_16x16x32_bf16(vf, ptB.s8, faccB[kt], 0, 0, 0);
    }
  }

  // ---- pair combine: mh=1 waves dump, mh=0 waves finalize
  if (mh == 1) {
#pragma unroll
    for (int kt = 0; kt < 4; kt++)
#pragma unroll
      for (int r = 0; r < 4; r++) {
        sfacc[nh][l][4 * kt + r]      = faccA[kt][r];
        sfacc[nh][l][16 + 4 * kt + r] = faccB[kt][r];
      }
    sfacc[nh][l][32] = esA4[0];
    sfacc[nh][l][33] = esB4[0];
  }
  __syncthreads();
  if (mh == 0) {
    float teA = esA4[0] + sfacc[nh][l][32];
    float teB = esB4[0] + sfacc[nh][l][33];
#pragma unroll
    for (int kt = 0; kt < 4; kt++)
#pragma unroll
      for (int r = 0; r < 4; r++) {
        faccA[kt][r] += sfacc[nh][l][4 * kt + r];
        faccB[kt][r] += sfacc[nh][l][16 + 4 * kt + r];
      }
    float invA = 1.0f / teA, invB = 1.0f / teB;
    unsigned short* fra = featT + ((size_t)b * NHW + n0 + 32 * nh + n16) * NCV + 4 * g;
    unsigned short* frb = fra + 16 * NCV;
#pragma unroll
    for (int kt = 0; kt < 4; kt++) {
      uint2 ua, ub;
      ua.x = pk2(faccA[kt][0] * invA, faccA[kt][1] * invA);
      ua.y = pk2(faccA[kt][2] * invA, faccA[kt][3] * invA);
      ub.x = pk2(faccB[kt][0] * invB, faccB[kt][1] * invB);
      ub.y = pk2(faccB[kt][2] * invB, faccB[kt][3] * invB);
      *(uint2*)(fra + 16 * kt) = ua;
      *(uint2*)(frb + 16 * kt) = ub;
    }
  }
}

// -------------------- out = gamma*(wa@feat + ba) + x  (MFMA, K=64)
__global__ __launch_bounds__(256) void outproj_kernel(const unsigned short* __restrict__ featT,
    const float* __restrict__ wa, const float* __restrict__ ba,
    const float* __restrict__ gamma, const float* __restrict__ x,
    float* __restrict__ out) {
  __shared__ unsigned short walds[NC][64];   // bf16, XOR-swizzled rows
  int tid = threadIdx.x;
  int w = tid >> 6, l = tid & 63, g = l >> 4, n16 = l & 15;
  int lbid = xcd_swz(blockIdx.x, NB * 64);
  int b  = lbid >> 6;
  int n0 = (lbid & 63) << 6;                 // 64 n per block
  {
    int row = tid >> 1, ch = (tid & 1) * 32;
    const float* src = wa + (size_t)row * NCV + ch;
    int rx = (row & 7) << 4;
    char* base = (char*)&walds[0][0] + row * 128;
#pragma unroll
    for (int q = 0; q < 4; q++) {
      float4 f0 = *(const float4*)(src + 8 * q);
      float4 f1 = *(const float4*)(src + 8 * q + 4);
      uint4 pv;
      pv.x = pk2(f0.x, f0.y); pv.y = pk2(f0.z, f0.w);
      pv.z = pk2(f1.x, f1.y); pv.w = pk2(f1.z, f1.w);
      int colb = ch * 2 + q * 16;
      *(uint4*)(base + (colb ^ rx)) = pv;
    }
  }
  __syncthreads();

  const unsigned short* fb = featT + ((size_t)b * NHW + n0 + n16) * NCV;
  short8 bfr[4][2];
#pragma unroll
  for (int nt = 0; nt < 4; nt++)
#pragma unroll
    for (int s = 0; s < 2; s++)
      bfr[nt][s] = *(const short8*)(fb + (size_t)nt * 16 * NCV + 32 * s + 8 * g);

  float g0 = gamma[0];
  f32x4 acc[2][4];
#pragma unroll
  for (int ti = 0; ti < 2; ti++) {
    int ot = 2 * w + ti;
    int row = 16 * ot + n16;
    char* abase = (char*)&walds[0][0] + row * 128;
    int rx = (row & 7) << 4;
    short8 af0 = *(const short8*)(abase + ((16 * g) ^ rx));
    short8 af1 = *(const short8*)(abase + ((64 + 16 * g) ^ rx));
    float b0 = ba[16 * ot + 4 * g + 0];
    float b1 = ba[16 * ot + 4 * g + 1];
    float b2 = ba[16 * ot + 4 * g + 2];
    float b3 = ba[16 * ot + 4 * g + 3];
#pragma unroll
    for (int nt = 0; nt < 4; nt++) {
      f32x4 c0 = {b0, b1, b2, b3};
      c0 = __builtin_amdgcn_mfma_f32_16x16x32_bf16(af0, bfr[nt][0], c0, 0, 0, 0);
      c0 = __builtin_amdgcn_mfma_f32_16x16x32_bf16(af1, bfr[nt][1], c0, 0, 0, 0);
      acc[ti][nt] = c0;
    }
  }
#pragma unroll
  for (int ti = 0; ti < 2; ti++) {
    int ot = 2 * w + ti;
#pragma unroll
    for (int nt = 0; nt < 4; nt++) {
#pragma unroll
      for (int r = 0; r < 4; r++) {
        size_t idx = ((size_t)b * NC + 16 * ot + 4 * g + r) * NHW + n0 + 16 * nt + n16;
        out[idx] = g0 * acc[ti][nt][r] + x[idx];
      }
    }
  }
}

extern "C" void kernel_launch(void* const* d_in, const int* in_sizes, int n_in,
                              void* d_out, int out_size, void* d_ws, size_t ws_size,
                              hipStream_t stream) {
  const float* x     = (const float*)d_in[0];
  const float* wq    = (const float*)d_in[1];
  const float* bq    = (const float*)d_in[2];
  const float* wk    = (const float*)d_in[3];
  const float* bk    = (const float*)d_in[4];
  const float* wv    = (const float*)d_in[5];
  const float* bv    = (const float*)d_in[6];
  const float* wa    = (const float*)d_in[7];
  const float* ba    = (const float*)d_in[8];
  const float* gamma = (const float*)d_in[9];
  float* out = (float*)d_out;

  unsigned short* kT    = (unsigned short*)d_ws;                 // 16*1024*16  = 512 KB
  unsigned short* vv    = kT + (size_t)NB * NHWP * NCQ;          // 16*64*1024  = 2 MB
  unsigned short* featT = vv + (size_t)NB * NCV * NHWP;          // 16*4096*64  = 8 MB

  projkv_kernel <<<NB * 5 * 16,  256, 0, stream>>>(x, wk, bk, wv, bv, kT, vv);
  attn_kernel   <<<NB * 64,      256, 0, stream>>>(x, wq, bq, kT, vv, featT);
  outproj_kernel<<<NB * 64,      256, 0, stream>>>(featT, wa, ba, gamma, x, out);
}

// Round 5
// 68.110 us; speedup vs baseline: 34.4583x; 1.1232x over previous
//
#include <hip/hip_runtime.h>
#include <math.h>

#define NB 16
#define NC 128
#define NHW 4096     // 64*64
#define NHWP 1024    // 32*32
#define NCQ 16       // C/8
#define NCV 64       // C/2
#define L2E 1.44269504f

typedef __attribute__((ext_vector_type(8))) short short8;
typedef __attribute__((ext_vector_type(4))) float f32x4;

__device__ inline unsigned short f2bf(float f) {
  unsigned u = __builtin_bit_cast(unsigned, f);
  u += 0x7fffu + ((u >> 16) & 1u);          // RNE
  return (unsigned short)(u >> 16);
}

__device__ inline unsigned pk2(float lo, float hi) {
  unsigned r;
  asm("v_cvt_pk_bf16_f32 %0, %1, %2" : "=v"(r) : "v"(lo), "v"(hi));
  return r;
}

// XCD-aware chunked swizzle (grids are multiples of 8)
__device__ inline int xcd_swz(int bid, int nwg) {
  int cpx = nwg >> 3;
  return (bid & 7) * cpx + (bid >> 3);
}

// ---------------- fused pool + k,v proj, og-split (5) x mt (16) x cg-split (4)
// outputs: kT bf16 [b][m][16], vv bf16 [b][c][m]
// blocks lbid==0/1 additionally convert wq (x log2e) and wa to bf16.
__global__ __launch_bounds__(256) void projkv_kernel(const float* __restrict__ x,
    const float* __restrict__ wk, const float* __restrict__ bk,
    const float* __restrict__ wv, const float* __restrict__ bv,
    const float* __restrict__ wq, const float* __restrict__ wa,
    unsigned short* __restrict__ kT, unsigned short* __restrict__ vv,
    unsigned short* __restrict__ wqB, unsigned short* __restrict__ waB) {
  __shared__ float swT[NC][16];     // swT[c][o]
  __shared__ float pacc[3][64][17]; // cg 1..3 partials
  __shared__ float sbias[16];
  int lbid = xcd_swz(blockIdx.x, NB * 5 * 16);
  int tid = threadIdx.x;
  // piggyback weight conversion for the attention megakernel
  if (lbid == 0) {
    for (int i = tid; i < NCQ * NC; i += 256) wqB[i] = f2bf(wq[i] * L2E);
  } else if (lbid == 1) {
    for (int i = tid; i < NC * NCV; i += 256) waB[i] = f2bf(wa[i]);
  }
  int og = lbid % 5;
  int mt = (lbid / 5) & 15;
  int b  = lbid / 80;
  const float* wsrc = (og == 0) ? wk : (wv + (size_t)(og - 1) * 16 * NC);
  const float* bsrc = (og == 0) ? bk : (bv + (og - 1) * 16);
  for (int i = tid; i < NC * 16; i += 256) {
    int o = i >> 7, c = i & 127;
    swT[c][o] = wsrc[i];
  }
  if (tid < 16) sbias[tid] = bsrc[tid];
  __syncthreads();
  int ml = tid & 63, cg = tid >> 6;
  int m = mt * 64 + ml;
  int j = m & 31, i2 = m >> 5;
  const float* xb = x + ((size_t)b * NC + cg * 32) * NHW + (size_t)(2 * i2) * 64 + 2 * j;
  float acc[16];
#pragma unroll
  for (int o = 0; o < 16; o++) acc[o] = 0.f;
#pragma unroll 4
  for (int ci = 0; ci < 32; ci++) {
    int c = cg * 32 + ci;
    const float* xc = xb + (size_t)ci * NHW;
    float2 t0 = *(const float2*)xc;
    float2 t1 = *(const float2*)(xc + 64);
    float xv = fmaxf(fmaxf(t0.x, t0.y), fmaxf(t1.x, t1.y));   // 2x2 maxpool
    const float4* wr = (const float4*)&swT[c][0];
#pragma unroll
    for (int o4 = 0; o4 < 4; o4++) {
      float4 w4 = wr[o4];
      acc[4*o4+0] = fmaf(xv, w4.x, acc[4*o4+0]);
      acc[4*o4+1] = fmaf(xv, w4.y, acc[4*o4+1]);
      acc[4*o4+2] = fmaf(xv, w4.z, acc[4*o4+2]);
      acc[4*o4+3] = fmaf(xv, w4.w, acc[4*o4+3]);
    }
  }
  if (cg > 0) {
#pragma unroll
    for (int o = 0; o < 16; o++) pacc[cg - 1][ml][o] = acc[o];
  }
  __syncthreads();
  if (cg == 0) {
#pragma unroll
    for (int o = 0; o < 16; o++)
      acc[o] += pacc[0][ml][o] + pacc[1][ml][o] + pacc[2][ml][o] + sbias[o];
    if (og == 0) {
      unsigned short* kr = kT + ((size_t)b * NHWP + m) * NCQ;
      uint4 u0, u1;
      u0.x = pk2(acc[0],  acc[1]);  u0.y = pk2(acc[2],  acc[3]);
      u0.z = pk2(acc[4],  acc[5]);  u0.w = pk2(acc[6],  acc[7]);
      u1.x = pk2(acc[8],  acc[9]);  u1.y = pk2(acc[10], acc[11]);
      u1.z = pk2(acc[12], acc[13]); u1.w = pk2(acc[14], acc[15]);
      *(uint4*)kr = u0;
      *(uint4*)(kr + 8) = u1;
    } else {
      unsigned short* vr = vv + (size_t)b * NCV * NHWP + (size_t)(og - 1) * 16 * NHWP + m;
#pragma unroll
      for (int o = 0; o < 16; o++) vr[(size_t)o * NHWP] = f2bf(acc[o]);
    }
  }
}

// ------------- megakernel: Q-proj + attention + outproj + residual
// per block: 64 n. waves (nh,mh): 32n x 512m each, LDS pair-combine,
// feat staged in swizzled LDS, then out = gamma*(wa@feat+ba) + x.
__global__ __launch_bounds__(256) void attn_kernel(const float* __restrict__ x,
    const unsigned short* __restrict__ wqB, const float* __restrict__ bq,
    const unsigned short* __restrict__ kT, const unsigned short* __restrict__ vv,
    const unsigned short* __restrict__ waB, const float* __restrict__ ba,
    const float* __restrict__ gamma, float* __restrict__ out) {
  __shared__ unsigned short qlds[64][16];   // Q^T as [n][c] bf16 (log2e-scaled)
  __shared__ float sfacc[2][64][36];        // mh=1 partials: 32 facc + 2 esum
  __shared__ unsigned short featlds[64][64];// feat [n][c] bf16, XOR-swizzled
  int tid = threadIdx.x;
  int w = tid >> 6, l = tid & 63, g = l >> 4, n16 = l & 15;
  int nh = w & 1, mh = w >> 1;
  int lbid = xcd_swz(blockIdx.x, NB * 64);
  int b  = lbid >> 6;
  int n0 = (lbid & 63) << 6;                // 64 n per block

  // ---- fused Q projection: wave w computes Q^T[16c x 16n] tile w (wq pre-scaled)
  {
    f32x4 qacc;
#pragma unroll
    for (int r = 0; r < 4; r++) qacc[r] = bq[4 * g + r] * L2E;
#pragma unroll
    for (int s = 0; s < 4; s++) {
      short8 af = *(const short8*)&wqB[n16 * NC + 32 * s + 8 * g];
      const float* xc = x + ((size_t)b * NC + 32 * s + 8 * g) * NHW + n0 + 16 * w + n16;
      float xv[8];
#pragma unroll
      for (int jj = 0; jj < 8; jj++) xv[jj] = xc[(size_t)jj * NHW];
      union { short8 s8; uint4 u4; } bf_;
      bf_.u4.x = pk2(xv[0], xv[1]); bf_.u4.y = pk2(xv[2], xv[3]);
      bf_.u4.z = pk2(xv[4], xv[5]); bf_.u4.w = pk2(xv[6], xv[7]);
      qacc = __builtin_amdgcn_mfma_f32_16x16x32_bf16(af, bf_.s8, qacc, 0, 0, 0);
    }
    unsigned* qw = (unsigned*)&qlds[16 * w + n16][4 * g];
    qw[0] = pk2(qacc[0], qacc[1]);
    qw[1] = pk2(qacc[2], qacc[3]);
  }
  __syncthreads();

  short8 zf = {0, 0, 0, 0, 0, 0, 0, 0};
  short8 qfA = zf, qfB = zf;
  if (g < 2) {
    qfA = *(const short8*)&qlds[32 * nh + n16][8 * g];
    qfB = *(const short8*)&qlds[32 * nh + 16 + n16][8 * g];
  }
  short8 ones;
#pragma unroll
  for (int jj = 0; jj < 8; jj++) ones[jj] = (short)0x3F80;

  const unsigned short* kb = kT + (size_t)b * NHWP * NCQ;
  const unsigned short* vb = vv + (size_t)b * NCV * NHWP;
  f32x4 faccA[4], faccB[4];
#pragma unroll
  for (int kt = 0; kt < 4; kt++) {
    faccA[kt] = (f32x4){0.f, 0.f, 0.f, 0.f};
    faccB[kt] = (f32x4){0.f, 0.f, 0.f, 0.f};
  }
  f32x4 esA4 = {0.f, 0.f, 0.f, 0.f}, esB4 = {0.f, 0.f, 0.f, 0.f};
  int mr = 8 * (n16 >> 2) + (n16 & 3);      // sigma remap
  int mbase = mh << 9;                      // wave pair's 512-m half

#pragma unroll 2
  for (int mi = 0; mi < 16; mi++) {
    int m0 = mbase + 32 * mi;
    short8 a0 = zf, a1 = zf;
    if (g < 2) {
      a0 = *(const short8*)&kb[(size_t)(m0 + mr) * NCQ + 8 * g];
      a1 = *(const short8*)&kb[(size_t)(m0 + mr + 4) * NCQ + 8 * g];
    }
    f32x4 z = {0.f, 0.f, 0.f, 0.f};
    f32x4 s0A = __builtin_amdgcn_mfma_f32_16x16x32_bf16(a0, qfA, z, 0, 0, 0);
    f32x4 s1A = __builtin_amdgcn_mfma_f32_16x16x32_bf16(a1, qfA, z, 0, 0, 0);
    f32x4 s0B = __builtin_amdgcn_mfma_f32_16x16x32_bf16(a0, qfB, z, 0, 0, 0);
    f32x4 s1B = __builtin_amdgcn_mfma_f32_16x16x32_bf16(a1, qfB, z, 0, 0, 0);
    float eA0 = __builtin_amdgcn_exp2f(s0A[0]), eA1 = __builtin_amdgcn_exp2f(s0A[1]);
    float eA2 = __builtin_amdgcn_exp2f(s0A[2]), eA3 = __builtin_amdgcn_exp2f(s0A[3]);
    float eA4 = __builtin_amdgcn_exp2f(s1A[0]), eA5 = __builtin_amdgcn_exp2f(s1A[1]);
    float eA6 = __builtin_amdgcn_exp2f(s1A[2]), eA7 = __builtin_amdgcn_exp2f(s1A[3]);
    float eB0 = __builtin_amdgcn_exp2f(s0B[0]), eB1 = __builtin_amdgcn_exp2f(s0B[1]);
    float eB2 = __builtin_amdgcn_exp2f(s0B[2]), eB3 = __builtin_amdgcn_exp2f(s0B[3]);
    float eB4 = __builtin_amdgcn_exp2f(s1B[0]), eB5 = __builtin_amdgcn_exp2f(s1B[1]);
    float eB6 = __builtin_amdgcn_exp2f(s1B[2]), eB7 = __builtin_amdgcn_exp2f(s1B[3]);
    union { short8 s8; uint4 u4; } ptA, ptB;
    ptA.u4.x = pk2(eA0, eA1); ptA.u4.y = pk2(eA2, eA3);
    ptA.u4.z = pk2(eA4, eA5); ptA.u4.w = pk2(eA6, eA7);
    ptB.u4.x = pk2(eB0, eB1); ptB.u4.y = pk2(eB2, eB3);
    ptB.u4.z = pk2(eB4, eB5); ptB.u4.w = pk2(eB6, eB7);
    esA4 = __builtin_amdgcn_mfma_f32_16x16x32_bf16(ones, ptA.s8, esA4, 0, 0, 0);
    esB4 = __builtin_amdgcn_mfma_f32_16x16x32_bf16(ones, ptB.s8, esB4, 0, 0, 0);
#pragma unroll
    for (int kt = 0; kt < 4; kt++) {
      short8 vf = *(const short8*)&vb[(size_t)(16 * kt + n16) * NHWP + m0 + 8 * g];
      faccA[kt] = __builtin_amdgcn_mfma_f32_16x16x32_bf16(vf, ptA.s8, faccA[kt], 0, 0, 0);
      faccB[kt] = __builtin_amdgcn_mfma_f32_16x16x32_bf16(vf, ptB.s8, faccB[kt], 0, 0, 0);
    }
  }

  // ---- pair combine: mh=1 waves dump, mh=0 waves finalize into featlds
  if (mh == 1) {
#pragma unroll
    for (int kt = 0; kt < 4; kt++)
#pragma unroll
      for (int r = 0; r < 4; r++) {
        sfacc[nh][l][4 * kt + r]      = faccA[kt][r];
        sfacc[nh][l][16 + 4 * kt + r] = faccB[kt][r];
      }
    sfacc[nh][l][32] = esA4[0];
    sfacc[nh][l][33] = esB4[0];
  }
  __syncthreads();
  if (mh == 0) {
    float teA = esA4[0] + sfacc[nh][l][32];
    float teB = esB4[0] + sfacc[nh][l][33];
#pragma unroll
    for (int kt = 0; kt < 4; kt++)
#pragma unroll
      for (int r = 0; r < 4; r++) {
        faccA[kt][r] += sfacc[nh][l][4 * kt + r];
        faccB[kt][r] += sfacc[nh][l][16 + 4 * kt + r];
      }
    float invA = 1.0f / teA, invB = 1.0f / teB;
    int na = 32 * nh + n16, nbw = na + 16;
    char* rowa = (char*)&featlds[0][0] + na * 128;
    char* rowb = (char*)&featlds[0][0] + nbw * 128;
    int rxa = (na & 7) << 4, rxb = (nbw & 7) << 4;
#pragma unroll
    for (int kt = 0; kt < 4; kt++) {
      uint2 ua, ub;
      ua.x = pk2(faccA[kt][0] * invA, faccA[kt][1] * invA);
      ua.y = pk2(faccA[kt][2] * invA, faccA[kt][3] * invA);
      ub.x = pk2(faccB[kt][0] * invB, faccB[kt][1] * invB);
      ub.y = pk2(faccB[kt][2] * invB, faccB[kt][3] * invB);
      int cb = (16 * kt + 4 * g) * 2;
      *(uint2*)(rowa + (cb ^ rxa)) = ua;
      *(uint2*)(rowb + (cb ^ rxb)) = ub;
    }
  }
  __syncthreads();

  // ---- fused outproj: out[128oc][64n] = gamma*(wa@feat + ba) + x
  short8 bfr[4][2];
#pragma unroll
  for (int nt = 0; nt < 4; nt++) {
    int nl = 16 * nt + n16;
    char* rowp = (char*)&featlds[0][0] + nl * 128;
    int rx = (nl & 7) << 4;
#pragma unroll
    for (int s = 0; s < 2; s++)
      bfr[nt][s] = *(const short8*)(rowp + (((32 * s + 8 * g) * 2) ^ rx));
  }
  float g0 = gamma[0];
#pragma unroll
  for (int ti = 0; ti < 2; ti++) {
    int ot = 2 * w + ti;
    short8 af0 = *(const short8*)&waB[(size_t)(16 * ot + n16) * NCV + 8 * g];
    short8 af1 = *(const short8*)&waB[(size_t)(16 * ot + n16) * NCV + 32 + 8 * g];
    float b0 = ba[16 * ot + 4 * g + 0];
    float b1 = ba[16 * ot + 4 * g + 1];
    float b2 = ba[16 * ot + 4 * g + 2];
    float b3 = ba[16 * ot + 4 * g + 3];
#pragma unroll
    for (int nt = 0; nt < 4; nt++) {
      f32x4 c0 = {b0, b1, b2, b3};
      c0 = __builtin_amdgcn_mfma_f32_16x16x32_bf16(af0, bfr[nt][0], c0, 0, 0, 0);
      c0 = __builtin_amdgcn_mfma_f32_16x16x32_bf16(af1, bfr[nt][1], c0, 0, 0, 0);
#pragma unroll
      for (int r = 0; r < 4; r++) {
        size_t idx = ((size_t)b * NC + 16 * ot + 4 * g + r) * NHW + n0 + 16 * nt + n16;
        out[idx] = g0 * c0[r] + x[idx];
      }
    }
  }
}

extern "C" void kernel_launch(void* const* d_in, const int* in_sizes, int n_in,
                              void* d_out, int out_size, void* d_ws, size_t ws_size,
                              hipStream_t stream) {
  const float* x     = (const float*)d_in[0];
  const float* wq    = (const float*)d_in[1];
  const float* bq    = (const float*)d_in[2];
  const float* wk    = (const float*)d_in[3];
  const float* bk    = (const float*)d_in[4];
  const float* wv    = (const float*)d_in[5];
  const float* bv    = (const float*)d_in[6];
  const float* wa    = (const float*)d_in[7];
  const float* ba    = (const float*)d_in[8];
  const float* gamma = (const float*)d_in[9];
  float* out = (float*)d_out;

  unsigned short* kT  = (unsigned short*)d_ws;                 // 16*1024*16  = 512 KB
  unsigned short* vv  = kT + (size_t)NB * NHWP * NCQ;          // 16*64*1024  = 2 MB
  unsigned short* wqB = vv + (size_t)NB * NCV * NHWP;          // 16*128      = 4 KB
  unsigned short* waB = wqB + (size_t)NCQ * NC;                // 128*64      = 16 KB

  projkv_kernel<<<NB * 5 * 16, 256, 0, stream>>>(x, wk, bk, wv, bv, wq, wa,
                                                 kT, vv, wqB, waB);
  attn_kernel  <<<NB * 64,     256, 0, stream>>>(x, wqB, bq, kT, vv, waB, ba,
                                                 gamma, out);
}

// Round 6
// 65.277 us; speedup vs baseline: 35.9536x; 1.0434x over previous
//
#include <hip/hip_runtime.h>
#include <math.h>

#define NB 16
#define NC 128
#define NHW 4096     // 64*64
#define NHWP 1024    // 32*32
#define NCQ 16       // C/8
#define NCV 64       // C/2
#define L2E 1.44269504f

typedef __attribute__((ext_vector_type(8))) short short8;
typedef __attribute__((ext_vector_type(4))) float f32x4;

__device__ inline unsigned short f2bf(float f) {
  unsigned u = __builtin_bit_cast(unsigned, f);
  u += 0x7fffu + ((u >> 16) & 1u);          // RNE
  return (unsigned short)(u >> 16);
}

__device__ inline unsigned pk2(float lo, float hi) {
  unsigned r;
  asm("v_cvt_pk_bf16_f32 %0, %1, %2" : "=v"(r) : "v"(lo), "v"(hi));
  return r;
}

// XCD-aware chunked swizzle (grids are multiples of 8)
__device__ inline int xcd_swz(int bid, int nwg) {
  int cpx = nwg >> 3;
  return (bid & 7) * cpx + (bid >> 3);
}

// ---------------- fused pool + k,v proj, og-split (5) x mt (16) x cg-split (4)
// outputs: kT bf16 [b][m][16], vv bf16 [b][c][m]
// blocks lbid==0/1 additionally convert wq (x log2e) and wa to bf16.
__global__ __launch_bounds__(256) void projkv_kernel(const float* __restrict__ x,
    const float* __restrict__ wk, const float* __restrict__ bk,
    const float* __restrict__ wv, const float* __restrict__ bv,
    const float* __restrict__ wq, const float* __restrict__ wa,
    unsigned short* __restrict__ kT, unsigned short* __restrict__ vv,
    unsigned short* __restrict__ wqB, unsigned short* __restrict__ waB) {
  __shared__ float swT[NC][16];     // swT[c][o]
  __shared__ float pacc[3][64][17]; // cg 1..3 partials
  __shared__ float sbias[16];
  int lbid = xcd_swz(blockIdx.x, NB * 5 * 16);
  int tid = threadIdx.x;
  // piggyback weight conversion for the attention megakernel
  if (lbid == 0) {
    for (int i = tid; i < NCQ * NC; i += 256) wqB[i] = f2bf(wq[i] * L2E);
  } else if (lbid == 1) {
    for (int i = tid; i < NC * NCV; i += 256) waB[i] = f2bf(wa[i]);
  }
  int og = lbid % 5;
  int mt = (lbid / 5) & 15;
  int b  = lbid / 80;
  const float* wsrc = (og == 0) ? wk : (wv + (size_t)(og - 1) * 16 * NC);
  const float* bsrc = (og == 0) ? bk : (bv + (og - 1) * 16);
  for (int i = tid; i < NC * 16; i += 256) {
    int o = i >> 7, c = i & 127;
    swT[c][o] = wsrc[i];
  }
  if (tid < 16) sbias[tid] = bsrc[tid];
  __syncthreads();
  int ml = tid & 63, cg = tid >> 6;
  int m = mt * 64 + ml;
  int j = m & 31, i2 = m >> 5;
  const float* xb = x + ((size_t)b * NC + cg * 32) * NHW + (size_t)(2 * i2) * 64 + 2 * j;
  float acc[16];
#pragma unroll
  for (int o = 0; o < 16; o++) acc[o] = 0.f;
#pragma unroll 4
  for (int ci = 0; ci < 32; ci++) {
    int c = cg * 32 + ci;
    const float* xc = xb + (size_t)ci * NHW;
    float2 t0 = *(const float2*)xc;
    float2 t1 = *(const float2*)(xc + 64);
    float xv = fmaxf(fmaxf(t0.x, t0.y), fmaxf(t1.x, t1.y));   // 2x2 maxpool
    const float4* wr = (const float4*)&swT[c][0];
#pragma unroll
    for (int o4 = 0; o4 < 4; o4++) {
      float4 w4 = wr[o4];
      acc[4*o4+0] = fmaf(xv, w4.x, acc[4*o4+0]);
      acc[4*o4+1] = fmaf(xv, w4.y, acc[4*o4+1]);
      acc[4*o4+2] = fmaf(xv, w4.z, acc[4*o4+2]);
      acc[4*o4+3] = fmaf(xv, w4.w, acc[4*o4+3]);
    }
  }
  if (cg > 0) {
#pragma unroll
    for (int o = 0; o < 16; o++) pacc[cg - 1][ml][o] = acc[o];
  }
  __syncthreads();
  if (cg == 0) {
#pragma unroll
    for (int o = 0; o < 16; o++)
      acc[o] += pacc[0][ml][o] + pacc[1][ml][o] + pacc[2][ml][o] + sbias[o];
    if (og == 0) {
      unsigned short* kr = kT + ((size_t)b * NHWP + m) * NCQ;
      uint4 u0, u1;
      u0.x = pk2(acc[0],  acc[1]);  u0.y = pk2(acc[2],  acc[3]);
      u0.z = pk2(acc[4],  acc[5]);  u0.w = pk2(acc[6],  acc[7]);
      u1.x = pk2(acc[8],  acc[9]);  u1.y = pk2(acc[10], acc[11]);
      u1.z = pk2(acc[12], acc[13]); u1.w = pk2(acc[14], acc[15]);
      *(uint4*)kr = u0;
      *(uint4*)(kr + 8) = u1;
    } else {
      unsigned short* vr = vv + (size_t)b * NCV * NHWP + (size_t)(og - 1) * 16 * NHWP + m;
#pragma unroll
      for (int o = 0; o < 16; o++) vr[(size_t)o * NHWP] = f2bf(acc[o]);
    }
  }
}

// ------------- megakernel: Q-proj + attention + outproj + residual
// per block: 64 n. waves (nh,mh): 32n x 512m each, LDS pair-combine,
// feat staged in swizzled LDS, then out = gamma*(wa@feat+ba) + x.
// Main loop: all loads unconditional (zero-padded qlds, g&1 K addressing).
__global__ __launch_bounds__(256) void attn_kernel(const float* __restrict__ x,
    const unsigned short* __restrict__ wqB, const float* __restrict__ bq,
    const unsigned short* __restrict__ kT, const unsigned short* __restrict__ vv,
    const unsigned short* __restrict__ waB, const float* __restrict__ ba,
    const float* __restrict__ gamma, float* __restrict__ out) {
  __shared__ unsigned short qlds[64][32];   // Q^T [n][k] bf16, k16..31 = 0
  __shared__ float sfacc[2][64][36];        // mh=1 partials: 32 facc + 2 esum
  __shared__ unsigned short featlds[64][64];// feat [n][c] bf16, XOR-swizzled
  int tid = threadIdx.x;
  int w = tid >> 6, l = tid & 63, g = l >> 4, n16 = l & 15;
  int nh = w & 1, mh = w >> 1;
  int lbid = xcd_swz(blockIdx.x, NB * 64);
  int b  = lbid >> 6;
  int n0 = (lbid & 63) << 6;                // 64 n per block

  // zero the k=16..31 half of qlds (read by g>=2 B-frags)
  for (int i = tid; i < 64 * 8; i += 256)
    ((unsigned*)&qlds[i >> 3][16])[i & 7] = 0;

  // ---- fused Q projection: wave w computes Q^T[16c x 16n] tile w (wq pre-scaled)
  {
    f32x4 qacc;
#pragma unroll
    for (int r = 0; r < 4; r++) qacc[r] = bq[4 * g + r] * L2E;
#pragma unroll
    for (int s = 0; s < 4; s++) {
      short8 af = *(const short8*)&wqB[n16 * NC + 32 * s + 8 * g];
      const float* xc = x + ((size_t)b * NC + 32 * s + 8 * g) * NHW + n0 + 16 * w + n16;
      float xv[8];
#pragma unroll
      for (int jj = 0; jj < 8; jj++) xv[jj] = xc[(size_t)jj * NHW];
      union { short8 s8; uint4 u4; } bf_;
      bf_.u4.x = pk2(xv[0], xv[1]); bf_.u4.y = pk2(xv[2], xv[3]);
      bf_.u4.z = pk2(xv[4], xv[5]); bf_.u4.w = pk2(xv[6], xv[7]);
      qacc = __builtin_amdgcn_mfma_f32_16x16x32_bf16(af, bf_.s8, qacc, 0, 0, 0);
    }
    unsigned* qw = (unsigned*)&qlds[16 * w + n16][4 * g];
    qw[0] = pk2(qacc[0], qacc[1]);
    qw[1] = pk2(qacc[2], qacc[3]);
  }
  __syncthreads();

  // B-frags: unconditional 16B; g>=2 lanes read the zeroed k-half
  short8 qfA = *(const short8*)&qlds[32 * nh + n16][8 * g];
  short8 qfB = *(const short8*)&qlds[32 * nh + 16 + n16][8 * g];
  short8 ones;
#pragma unroll
  for (int jj = 0; jj < 8; jj++) ones[jj] = (short)0x3F80;

  const unsigned short* kb = kT + (size_t)b * NHWP * NCQ;
  const unsigned short* vb = vv + (size_t)b * NCV * NHWP;
  f32x4 faccA[4], faccB[4];
#pragma unroll
  for (int kt = 0; kt < 4; kt++) {
    faccA[kt] = (f32x4){0.f, 0.f, 0.f, 0.f};
    faccB[kt] = (f32x4){0.f, 0.f, 0.f, 0.f};
  }
  f32x4 esA4 = {0.f, 0.f, 0.f, 0.f}, esB4 = {0.f, 0.f, 0.f, 0.f};
  int mr = 8 * (n16 >> 2) + (n16 & 3);      // sigma remap
  int koff = 8 * (g & 1);                   // g>=2 lanes load junk x zero-B
  int mbase = mh << 9;                      // wave pair's 512-m half

#pragma unroll 4
  for (int mi = 0; mi < 16; mi++) {
    int m0 = mbase + 32 * mi;
    // ---- all loads first, unconditional, no exec-mask traffic
    short8 a0 = *(const short8*)&kb[(size_t)(m0 + mr) * NCQ + koff];
    short8 a1 = *(const short8*)&kb[(size_t)(m0 + mr + 4) * NCQ + koff];
    short8 vf0 = *(const short8*)&vb[(size_t)(n16)      * NHWP + m0 + 8 * g];
    short8 vf1 = *(const short8*)&vb[(size_t)(16 + n16) * NHWP + m0 + 8 * g];
    short8 vf2 = *(const short8*)&vb[(size_t)(32 + n16) * NHWP + m0 + 8 * g];
    short8 vf3 = *(const short8*)&vb[(size_t)(48 + n16) * NHWP + m0 + 8 * g];
    f32x4 z = {0.f, 0.f, 0.f, 0.f};
    f32x4 s0A = __builtin_amdgcn_mfma_f32_16x16x32_bf16(a0, qfA, z, 0, 0, 0);
    f32x4 s1A = __builtin_amdgcn_mfma_f32_16x16x32_bf16(a1, qfA, z, 0, 0, 0);
    f32x4 s0B = __builtin_amdgcn_mfma_f32_16x16x32_bf16(a0, qfB, z, 0, 0, 0);
    f32x4 s1B = __builtin_amdgcn_mfma_f32_16x16x32_bf16(a1, qfB, z, 0, 0, 0);
    float eA0 = __builtin_amdgcn_exp2f(s0A[0]), eA1 = __builtin_amdgcn_exp2f(s0A[1]);
    float eA2 = __builtin_amdgcn_exp2f(s0A[2]), eA3 = __builtin_amdgcn_exp2f(s0A[3]);
    float eA4 = __builtin_amdgcn_exp2f(s1A[0]), eA5 = __builtin_amdgcn_exp2f(s1A[1]);
    float eA6 = __builtin_amdgcn_exp2f(s1A[2]), eA7 = __builtin_amdgcn_exp2f(s1A[3]);
    float eB0 = __builtin_amdgcn_exp2f(s0B[0]), eB1 = __builtin_amdgcn_exp2f(s0B[1]);
    float eB2 = __builtin_amdgcn_exp2f(s0B[2]), eB3 = __builtin_amdgcn_exp2f(s0B[3]);
    float eB4 = __builtin_amdgcn_exp2f(s1B[0]), eB5 = __builtin_amdgcn_exp2f(s1B[1]);
    float eB6 = __builtin_amdgcn_exp2f(s1B[2]), eB7 = __builtin_amdgcn_exp2f(s1B[3]);
    union { short8 s8; uint4 u4; } ptA, ptB;
    ptA.u4.x = pk2(eA0, eA1); ptA.u4.y = pk2(eA2, eA3);
    ptA.u4.z = pk2(eA4, eA5); ptA.u4.w = pk2(eA6, eA7);
    ptB.u4.x = pk2(eB0, eB1); ptB.u4.y = pk2(eB2, eB3);
    ptB.u4.z = pk2(eB4, eB5); ptB.u4.w = pk2(eB6, eB7);
    esA4 = __builtin_amdgcn_mfma_f32_16x16x32_bf16(ones, ptA.s8, esA4, 0, 0, 0);
    esB4 = __builtin_amdgcn_mfma_f32_16x16x32_bf16(ones, ptB.s8, esB4, 0, 0, 0);
    faccA[0] = __builtin_amdgcn_mfma_f32_16x16x32_bf16(vf0, ptA.s8, faccA[0], 0, 0, 0);
    faccB[0] = __builtin_amdgcn_mfma_f32_16x16x32_bf16(vf0, ptB.s8, faccB[0], 0, 0, 0);
    faccA[1] = __builtin_amdgcn_mfma_f32_16x16x32_bf16(vf1, ptA.s8, faccA[1], 0, 0, 0);
    faccB[1] = __builtin_amdgcn_mfma_f32_16x16x32_bf16(vf1, ptB.s8, faccB[1], 0, 0, 0);
    faccA[2] = __builtin_amdgcn_mfma_f32_16x16x32_bf16(vf2, ptA.s8, faccA[2], 0, 0, 0);
    faccB[2] = __builtin_amdgcn_mfma_f32_16x16x32_bf16(vf2, ptB.s8, faccB[2], 0, 0, 0);
    faccA[3] = __builtin_amdgcn_mfma_f32_16x16x32_bf16(vf3, ptA.s8, faccA[3], 0, 0, 0);
    faccB[3] = __builtin_amdgcn_mfma_f32_16x16x32_bf16(vf3, ptB.s8, faccB[3], 0, 0, 0);
  }

  // ---- pair combine: mh=1 waves dump, mh=0 waves finalize into featlds
  if (mh == 1) {
#pragma unroll
    for (int kt = 0; kt < 4; kt++)
#pragma unroll
      for (int r = 0; r < 4; r++) {
        sfacc[nh][l][4 * kt + r]      = faccA[kt][r];
        sfacc[nh][l][16 + 4 * kt + r] = faccB[kt][r];
      }
    sfacc[nh][l][32] = esA4[0];
    sfacc[nh][l][33] = esB4[0];
  }
  __syncthreads();
  if (mh == 0) {
    float teA = esA4[0] + sfacc[nh][l][32];
    float teB = esB4[0] + sfacc[nh][l][33];
#pragma unroll
    for (int kt = 0; kt < 4; kt++)
#pragma unroll
      for (int r = 0; r < 4; r++) {
        faccA[kt][r] += sfacc[nh][l][4 * kt + r];
        faccB[kt][r] += sfacc[nh][l][16 + 4 * kt + r];
      }
    float invA = 1.0f / teA, invB = 1.0f / teB;
    int na = 32 * nh + n16, nbw = na + 16;
    char* rowa = (char*)&featlds[0][0] + na * 128;
    char* rowb = (char*)&featlds[0][0] + nbw * 128;
    int rxa = (na & 7) << 4, rxb = (nbw & 7) << 4;
#pragma unroll
    for (int kt = 0; kt < 4; kt++) {
      uint2 ua, ub;
      ua.x = pk2(faccA[kt][0] * invA, faccA[kt][1] * invA);
      ua.y = pk2(faccA[kt][2] * invA, faccA[kt][3] * invA);
      ub.x = pk2(faccB[kt][0] * invB, faccB[kt][1] * invB);
      ub.y = pk2(faccB[kt][2] * invB, faccB[kt][3] * invB);
      int cb = (16 * kt + 4 * g) * 2;
      *(uint2*)(rowa + (cb ^ rxa)) = ua;
      *(uint2*)(rowb + (cb ^ rxb)) = ub;
    }
  }
  __syncthreads();

  // ---- fused outproj: out[128oc][64n] = gamma*(wa@feat + ba) + x
  short8 bfr[4][2];
#pragma unroll
  for (int nt = 0; nt < 4; nt++) {
    int nl = 16 * nt + n16;
    char* rowp = (char*)&featlds[0][0] + nl * 128;
    int rx = (nl & 7) << 4;
#pragma unroll
    for (int s = 0; s < 2; s++)
      bfr[nt][s] = *(const short8*)(rowp + (((32 * s + 8 * g) * 2) ^ rx));
  }
  float g0 = gamma[0];
#pragma unroll
  for (int ti = 0; ti < 2; ti++) {
    int ot = 2 * w + ti;
    short8 af0 = *(const short8*)&waB[(size_t)(16 * ot + n16) * NCV + 8 * g];
    short8 af1 = *(const short8*)&waB[(size_t)(16 * ot + n16) * NCV + 32 + 8 * g];
    float b0 = ba[16 * ot + 4 * g + 0];
    float b1 = ba[16 * ot + 4 * g + 1];
    float b2 = ba[16 * ot + 4 * g + 2];
    float b3 = ba[16 * ot + 4 * g + 3];
#pragma unroll
    for (int nt = 0; nt < 4; nt++) {
      f32x4 c0 = {b0, b1, b2, b3};
      c0 = __builtin_amdgcn_mfma_f32_16x16x32_bf16(af0, bfr[nt][0], c0, 0, 0, 0);
      c0 = __builtin_amdgcn_mfma_f32_16x16x32_bf16(af1, bfr[nt][1], c0, 0, 0, 0);
#pragma unroll
      for (int r = 0; r < 4; r++) {
        size_t idx = ((size_t)b * NC + 16 * ot + 4 * g + r) * NHW + n0 + 16 * nt + n16;
        out[idx] = g0 * c0[r] + x[idx];
      }
    }
  }
}

extern "C" void kernel_launch(void* const* d_in, const int* in_sizes, int n_in,
                              void* d_out, int out_size, void* d_ws, size_t ws_size,
                              hipStream_t stream) {
  const float* x     = (const float*)d_in[0];
  const float* wq    = (const float*)d_in[1];
  const float* bq    = (const float*)d_in[2];
  const float* wk    = (const float*)d_in[3];
  const float* bk    = (const float*)d_in[4];
  const float* wv    = (const float*)d_in[5];
  const float* bv    = (const float*)d_in[6];
  const float* wa    = (const float*)d_in[7];
  const float* ba    = (const float*)d_in[8];
  const float* gamma = (const float*)d_in[9];
  float* out = (float*)d_out;

  unsigned short* kT  = (unsigned short*)d_ws;                 // 16*1024*16  = 512 KB
  unsigned short* vv  = kT + (size_t)NB * NHWP * NCQ;          // 16*64*1024  = 2 MB
  unsigned short* wqB = vv + (size_t)NB * NCV * NHWP;          // 16*128      = 4 KB
  unsigned short* waB = wqB + (size_t)NCQ * NC;                // 128*64      = 16 KB

  projkv_kernel<<<NB * 5 * 16, 256, 0, stream>>>(x, wk, bk, wv, bv, wq, wa,
                                                 kT, vv, wqB, waB);
  attn_kernel  <<<NB * 64,     256, 0, stream>>>(x, wqB, bq, kT, vv, waB, ba,
                                                 gamma, out);
}